// Round 8
// baseline (1213.241 us; speedup 1.0000x reference)
//
#include <hip/hip_runtime.h>
#include <hip/hip_bf16.h>
#include <hip/hip_fp16.h>

// Problem constants (fixed by the reference).
#define BB   128
#define NN   500
#define NV   64000        // BB*NN nodes
#define EE   1048576      // edges
#define DD   128
#define FIN  5
#define VNN  10
#define NBUK 250          // dst>>8 buckets (250*256 = 64000)
#define BCAP 8192         // bucket capacity (expected 4194, >50 sigma margin)

typedef unsigned int   uint32;
typedef unsigned short u16b;
typedef __attribute__((ext_vector_type(8))) short short8;   // 8 bf16 (4 VGPRs)
typedef __attribute__((ext_vector_type(4))) float float4v;  // MFMA C/D

// fp32 param-block layout (element offsets)
#define P_ASRC  0          // 4*128
#define P_ADST  512        // 4*128
#define P_WE    1024       // 4*2*128
#define P_BIAS  2048       // 4*128
#define P_W5    2560       // 128
#define P_CVEC  2688       // 12
#define P_SC5   2700       // b5, as5, ad5
#define P_TOT   2816

// slice-major H layout: H[s][n][u], s in [0,8) 16-ch slices, u in [0,8) uint
// (bf16 channel pairs).  element index:
#define HIDXU(s, n, u) (((size_t)(s) * NV + (n)) * 8 + (u))

static __device__ __forceinline__ float bf2f(__hip_bfloat16 v) { return __bfloat162float(v); }
static __device__ __forceinline__ float lo2f(uint32 u) { return __uint_as_float(u << 16); }
static __device__ __forceinline__ float hi2f(uint32 u) { return __uint_as_float(u & 0xFFFF0000u); }
static __device__ __forceinline__ uint32 f2bf_bits(float f) {
    uint32 u = __float_as_uint(f);
    return (u + 0x7FFFu + ((u >> 16) & 1u)) >> 16;
}
static __device__ __forceinline__ uint32 pack2(float a, float b) {
    return (f2bf_bits(a) & 0xFFFFu) | (f2bf_bits(b) << 16);
}
static __device__ __forceinline__ float ldf(const void* p, int i, int flag) {
    return flag ? ((const float*)p)[i] : bf2f(((const __hip_bfloat16*)p)[i]);
}
static __device__ __forceinline__ float a2f(uint32 al) {
    return __half2float(__ushort_as_half((unsigned short)(al >> 16)));
}

// ---------------------------------------------------------------------------
__global__ void sniff_kernel(const unsigned short* __restrict__ p16, int* __restrict__ FLAG) {
    __shared__ int sHigh, sZero;
    if (threadIdx.x == 0) { sHigh = 0; sZero = 0; }
    __syncthreads();
    unsigned short v = p16[2 * threadIdx.x];
    if (v >= 0x8000u) atomicOr(&sHigh, 1);
    if (v == 0)       atomicAdd(&sZero, 1);
    __syncthreads();
    if (threadIdx.x == 0) FLAG[0] = (sHigh || sZero >= 128) ? 1 : 0;
}

__global__ void zero_out_kernel(void* __restrict__ out, const int* __restrict__ FLAG, float tag) {
    int i = blockIdx.x * blockDim.x + threadIdx.x;
    if (i >= NV) return;
    float v = (i == 0) ? tag : 0.f;
    if (FLAG[0]) ((float*)out)[i] = v;
    else         ((u16b*)out)[i] = (u16b)f2bf_bits(v);
}

// ---------------------------------------------------------------------------
__global__ void prep_kernel(const void* __restrict__ Wes, const void* __restrict__ aeg,
                            const void* __restrict__ We5, const void* __restrict__ ae5,
                            const void* __restrict__ asr, const void* __restrict__ ads,
                            const void* __restrict__ bs, const void* __restrict__ W5,
                            const void* __restrict__ b5, const void* __restrict__ as5,
                            const void* __restrict__ ad5, const int* __restrict__ FLAG,
                            float* __restrict__ PAR) {
    const int flag = FLAG[0];
    if (blockIdx.x == 0) {
        for (int i = threadIdx.x; i < 512; i += 256) PAR[P_ASRC + i] = ldf(asr, i, flag);
    } else if (blockIdx.x == 1) {
        for (int i = threadIdx.x; i < 512; i += 256) PAR[P_ADST + i] = ldf(ads, i, flag);
    } else if (blockIdx.x == 2) {
        for (int i = threadIdx.x; i < 1024; i += 256) PAR[P_WE + i] = ldf(Wes, i, flag);
    } else if (blockIdx.x == 3) {
        for (int i = threadIdx.x; i < 512; i += 256) PAR[P_BIAS + i] = ldf(bs, i, flag);
    } else if (blockIdx.x == 4) {
        int tid = threadIdx.x;
        if (tid < 128) {
            PAR[P_W5 + tid] = ldf(W5, tid, flag);
        } else if (tid < 136) {
            int l = (tid - 128) >> 1, r = (tid - 128) & 1;
            float s = 0.f;
            for (int ch = 0; ch < DD; ++ch)
                s += ldf(Wes, l * 256 + r * DD + ch, flag) * ldf(aeg, l * DD + ch, flag);
            PAR[P_CVEC + l * 2 + r] = s;
        } else if (tid == 136) {
            float ae = ldf(ae5, 0, flag);
            float w0 = ldf(We5, 0, flag), w1 = ldf(We5, 1, flag);
            PAR[P_CVEC + 8] = w0 * ae; PAR[P_CVEC + 9] = w1 * ae;
            PAR[P_CVEC + 10] = w0;     PAR[P_CVEC + 11] = w1;
            PAR[P_SC5 + 0] = ldf(b5, 0, flag);
            PAR[P_SC5 + 1] = ldf(as5, 0, flag);
            PAR[P_SC5 + 2] = ldf(ad5, 0, flag);
        }
    }
}

// ---------------------------------------------------------------------------
// prepack W into MFMA B-fragment layout (unchanged by H slicing).
__global__ __launch_bounds__(256) void prepack_kernel(const void* __restrict__ Ws,
                                                      const int* __restrict__ FLAG,
                                                      u16b* __restrict__ WB) {
    const int flag = FLAG[0];
    int t = blockIdx.x * 256 + threadIdx.x;
    int lane = t & 63;
    int frag = t >> 6;
    int nchunk = frag & 7, kblk = (frag >> 3) & 3, l = frag >> 5;
    int n = nchunk * 16 + (lane & 15);
    int kbase = kblk * 32 + (lane >> 4) * 8;
#pragma unroll
    for (int j = 0; j < 8; ++j) {
        int idx = l * 16384 + (kbase + j) * 128 + n;
        u16b bits = flag ? (u16b)f2bf_bits(((const float*)Ws)[idx])
                         : ((const u16b*)Ws)[idx];
        WB[(size_t)t * 8 + j] = bits;
    }
}

// ---------------------------------------------------------------------------
// input projection -> slice-major H0
__global__ __launch_bounds__(256) void proj_kernel(
        const void* __restrict__ x, const void* __restrict__ pW,
        const void* __restrict__ pb, const int* __restrict__ curr,
        const void* __restrict__ vge, const void* __restrict__ vnd,
        const int* __restrict__ FLAG, uint32* __restrict__ H) {
    const int flag = FLAG[0];
    const int n = blockIdx.x * 4 + (threadIdx.x >> 6);
    const int lane = threadIdx.x & 63;
    const int b = n / NN;
    int cv = curr[b]; if ((unsigned)cv >= VNN) cv = 0;
    float xv[FIN];
#pragma unroll
    for (int k = 0; k < FIN; ++k) xv[k] = ldf(x, n * FIN + k, flag);
    const int ch = lane * 2;
    float s0 = ldf(pb, ch, flag), s1 = ldf(pb, ch + 1, flag);
#pragma unroll
    for (int k = 0; k < FIN; ++k) {
        s0 = fmaf(xv[k], ldf(pW, k * DD + ch, flag), s0);
        s1 = fmaf(xv[k], ldf(pW, k * DD + ch + 1, flag), s1);
    }
    s0 = (s0 > 0.f) ? s0 : 0.01f * s0;
    s1 = (s1 > 0.f) ? s1 : 0.01f * s1;
    s0 += ldf(vge, b * DD + ch, flag) + ldf(vnd, (b * VNN + cv) * DD + ch, flag);
    s1 += ldf(vge, b * DD + ch + 1, flag) + ldf(vnd, (b * VNN + cv) * DD + ch + 1, flag);
    H[HIDXU(lane >> 3, n, lane & 7)] = pack2(s0, s1);
}

// ---------------------------------------------------------------------------
// CSR build (2-level bucket sort), E1 = {src u16 | alpha fp16<<16} SoA.
__global__ void init_kernel(int* __restrict__ gcur, int* __restrict__ counts) {
    int t = blockIdx.x * 256 + threadIdx.x;
    if (t < NBUK) gcur[t] = t * BCAP;
    if (t < 512) counts[NV + t] = 0;
}

__global__ __launch_bounds__(256) void bucketize_kernel(
        const int* __restrict__ src, const int* __restrict__ dst,
        const void* __restrict__ eaP, const int* __restrict__ FLAG,
        int* __restrict__ gcur, uint32* __restrict__ bukx, uint32* __restrict__ buky) {
    __shared__ int cnt[256];
    __shared__ int cur[256];
    const int flag = FLAG[0];
    const int t = threadIdx.x;
    const int e0 = blockIdx.x * 4096;
    cnt[t] = 0;
    __syncthreads();
    int d[16];
#pragma unroll
    for (int i = 0; i < 16; ++i) {
        d[i] = dst[e0 + i * 256 + t];
        if ((unsigned)d[i] >= NV) d[i] = -1;
        if (d[i] >= 0) atomicAdd(&cnt[d[i] >> 8], 1);
    }
    __syncthreads();
    if (t < NBUK) {
        int c = cnt[t];
        cur[t] = c ? atomicAdd(&gcur[t], c) : 0;
    }
    __syncthreads();
#pragma unroll
    for (int i = 0; i < 16; ++i) {
        if (d[i] < 0) continue;
        int e = e0 + i * 256 + t;
        int b = d[i] >> 8;
        int s = src[e];
        if ((unsigned)s >= NV) s = 0;
        uint32 eb;
        if (flag) { float2 v = ((const float2*)eaP)[e]; eb = pack2(v.x, v.y); }
        else      eb = ((const uint32*)eaP)[e];
        int p = atomicAdd(&cur[b], 1);
        if (p < (b + 1) * BCAP) {
            bukx[p] = (uint32)((s & 0xFFFF) | ((d[i] & 255) << 16));
            buky[p] = eb;
        }
    }
}

__global__ __launch_bounds__(256) void bcount_kernel(
        const uint32* __restrict__ bukx, const int* __restrict__ gcur,
        int* __restrict__ counts) {
    __shared__ int c[256];
    const int b = blockIdx.x, t = threadIdx.x;
    c[t] = 0;
    __syncthreads();
    const int base = b * BCAP;
    int cnt = gcur[b] - base;
    if (cnt > BCAP) cnt = BCAP;
    for (int i = t; i < cnt; i += 256)
        atomicAdd(&c[(bukx[base + i] >> 16) & 255], 1);
    __syncthreads();
    counts[b * 256 + t] = c[t];
}

__global__ __launch_bounds__(256) void scan1_kernel(const int* __restrict__ counts,
                                                    int* __restrict__ row_ptr,
                                                    int* __restrict__ partials) {
    __shared__ int sdata[256];
    int tid = threadIdx.x;
    int4 v = ((const int4*)counts)[blockIdx.x * 256 + tid];
    int sum = v.x + v.y + v.z + v.w;
    sdata[tid] = sum;
    __syncthreads();
    int acc = sum;
    for (int off = 1; off < 256; off <<= 1) {
        int t = (tid >= off) ? sdata[tid - off] : 0;
        __syncthreads();
        acc += t;
        sdata[tid] = acc;
        __syncthreads();
    }
    int excl = acc - sum;
    int base = blockIdx.x * 1024 + tid * 4;
    int run = excl;
    if (base + 0 <= NV) row_ptr[base + 0] = run; run += v.x;
    if (base + 1 <= NV) row_ptr[base + 1] = run; run += v.y;
    if (base + 2 <= NV) row_ptr[base + 2] = run; run += v.z;
    if (base + 3 <= NV) row_ptr[base + 3] = run;
    if (tid == 255) partials[blockIdx.x] = acc;
}

__global__ __launch_bounds__(64) void scan2_kernel(const int* __restrict__ partials,
                                                   int* __restrict__ boff, int nb) {
    int lane = threadIdx.x;
    int v = (lane < nb) ? partials[lane] : 0;
    int orig = v;
#pragma unroll
    for (int off = 1; off < 64; off <<= 1) {
        int t = __shfl_up(v, off, 64);
        if (lane >= off) v += t;
    }
    boff[lane] = v - orig;
}

__global__ __launch_bounds__(256) void scan3_kernel(int* __restrict__ row_ptr,
                                                    const int* __restrict__ boff) {
    int add = boff[blockIdx.x];
    int base = blockIdx.x * 1024 + threadIdx.x * 4;
#pragma unroll
    for (int j = 0; j < 4; ++j) {
        int i = base + j;
        if (i <= NV) row_ptr[i] += add;
    }
}

__global__ __launch_bounds__(256) void bscatter_kernel(
        const uint32* __restrict__ bukx, const uint32* __restrict__ buky,
        const int* __restrict__ gcur, const int* __restrict__ row_ptr,
        uint32* __restrict__ e1, uint32* __restrict__ csr_ea) {
    __shared__ int cur[256];
    const int b = blockIdx.x, t = threadIdx.x;
    cur[t] = row_ptr[b * 256 + t];
    __syncthreads();
    const int base = b * BCAP;
    int cnt = gcur[b] - base;
    if (cnt > BCAP) cnt = BCAP;
    for (int i = t; i < cnt; i += 256) {
        uint32 x = bukx[base + i];
        uint32 y = buky[base + i];
        int p = atomicAdd(&cur[(x >> 16) & 255], 1);
        e1[p] = x & 0xFFFFu;
        csr_ea[p] = y;
    }
}

// ---------------------------------------------------------------------------
// MFMA GEMM over slice-major H: HW = H @ W + fused attention dots.
__global__ __launch_bounds__(256) void gemm_kernel(
        const uint32* __restrict__ Hu, const u16b* __restrict__ WBl,
        const float* __restrict__ PARl, uint32* __restrict__ HWu,
        float* __restrict__ ssrc, float* __restrict__ sdst) {
    __shared__ float hs[64 * 129];
    __shared__ float pp[512];
    const int tid = threadIdx.x;
    const int lane = tid & 63;
    const int wave = tid >> 6;
    const int quad = lane >> 4;
    const int n0 = blockIdx.x * 64;
    const int m = n0 + wave * 16 + (lane & 15);

    // A fragments from slice-major H: k-block kb -> slice kb*2+(quad>>1),
    // uint offset (quad&1)*4 (16B contiguous per lane).
    const int sA = quad >> 1, uA = (quad & 1) * 4;
    short8 a0 = *(const short8*)(Hu + HIDXU(0 + sA, m, uA));
    short8 a1 = *(const short8*)(Hu + HIDXU(2 + sA, m, uA));
    short8 a2 = *(const short8*)(Hu + HIDXU(4 + sA, m, uA));
    short8 a3 = *(const short8*)(Hu + HIDXU(6 + sA, m, uA));

#pragma unroll
    for (int nt = 0; nt < 8; ++nt) {
        const u16b* bbase = WBl + ((size_t)nt * 512 + lane * 8);
        short8 b0 = *(const short8*)(bbase + 0 * 4096);
        short8 b1 = *(const short8*)(bbase + 1 * 4096);
        short8 b2 = *(const short8*)(bbase + 2 * 4096);
        short8 b3 = *(const short8*)(bbase + 3 * 4096);
        float4v acc = {0.f, 0.f, 0.f, 0.f};
        acc = __builtin_amdgcn_mfma_f32_16x16x32_bf16(a0, b0, acc, 0, 0, 0);
        acc = __builtin_amdgcn_mfma_f32_16x16x32_bf16(a1, b1, acc, 0, 0, 0);
        acc = __builtin_amdgcn_mfma_f32_16x16x32_bf16(a2, b2, acc, 0, 0, 0);
        acc = __builtin_amdgcn_mfma_f32_16x16x32_bf16(a3, b3, acc, 0, 0, 0);
#pragma unroll
        for (int r = 0; r < 4; ++r)
            hs[(wave * 16 + quad * 4 + r) * 129 + nt * 16 + (lane & 15)] = acc[r];
    }
    __syncthreads();

    {
        const int mn = tid & 63, cg = tid >> 6;
        const float* Asr = PARl + P_ASRC;
        const float* Ads = PARl + P_ADST;
        const float* row = hs + mn * 129 + cg * 32;
        float ps = 0.f, pd = 0.f;
#pragma unroll
        for (int j = 0; j < 32; ++j) {
            float v = row[j];
            ps = fmaf(v, Asr[cg * 32 + j], ps);
            pd = fmaf(v, Ads[cg * 32 + j], pd);
        }
        pp[tid] = ps; pp[256 + tid] = pd;
    }
    __syncthreads();
    if (tid < 64) {
        ssrc[n0 + tid] = pp[tid] + pp[64 + tid] + pp[128 + tid] + pp[192 + tid];
        sdst[n0 + tid] = pp[256 + tid] + pp[320 + tid] + pp[384 + tid] + pp[448 + tid];
    }

    // slice-major bf16 store: f -> (s, n, u)
#pragma unroll
    for (int it = 0; it < 16; ++it) {
        int f = it * 256 + tid;
        int u = f & 7, n = (f >> 3) & 63, s = f >> 9;
        const float* p = hs + n * 129 + s * 16 + u * 2;
        HWu[HIDXU(s, n0 + n, u)] = pack2(p[0], p[1]);
    }
}

// ---------------------------------------------------------------------------
// attn: per-node softmax; writes alpha (fp16) into E1 high16 and
// (sx*inv, sy*inv) into SXY. One wave per node.
__global__ __launch_bounds__(256) void attn_kernel(
        const float* __restrict__ ssrc, const float* __restrict__ sdst,
        uint32* __restrict__ e1, const uint32* __restrict__ csr_ea,
        const int* __restrict__ row_ptr, const float* __restrict__ PAR,
        int layer, float2* __restrict__ SXY) {
    const int lane = threadIdx.x & 63;
    const int n = blockIdx.x * 4 + (threadIdx.x >> 6);
    const int begin = __builtin_amdgcn_readfirstlane(row_ptr[n]);
    const int deg   = __builtin_amdgcn_readfirstlane(row_ptr[n + 1]) - begin;
    const float c0 = PAR[P_CVEC + 2 * layer], c1 = PAR[P_CVEC + 2 * layer + 1];
    const float sd = sdst[n];

    uint32 ev = 0, eb = 0;
    float L = -3.4e38f;
    if (lane < deg) {
        ev = e1[begin + lane];
        eb = csr_ea[begin + lane];
        L = fmaf(hi2f(eb), c1, fmaf(lo2f(eb), c0, ssrc[ev & 0xFFFFu] + sd));
        L = (L > 0.f) ? L : 0.2f * L;
    }
    float m = L;
    for (int j0 = 64; j0 < deg; j0 += 64) {        // essentially never
        int j = j0 + lane;
        if (j < deg) {
            uint32 e2 = e1[begin + j], b2 = csr_ea[begin + j];
            float L2 = fmaf(hi2f(b2), c1, fmaf(lo2f(b2), c0, ssrc[e2 & 0xFFFFu] + sd));
            L2 = (L2 > 0.f) ? L2 : 0.2f * L2;
            m = fmaxf(m, L2);
        }
    }
#pragma unroll
    for (int o = 32; o; o >>= 1) m = fmaxf(m, __shfl_xor(m, o, 64));

    float ex = (lane < deg) ? __expf(L - m) : 0.f;
    float dsum = ex, sx = ex * lo2f(eb), sy = ex * hi2f(eb);
    for (int j0 = 64; j0 < deg; j0 += 64) {
        int j = j0 + lane;
        if (j < deg) {
            uint32 e2 = e1[begin + j], b2 = csr_ea[begin + j];
            float L2 = fmaf(hi2f(b2), c1, fmaf(lo2f(b2), c0, ssrc[e2 & 0xFFFFu] + sd));
            L2 = (L2 > 0.f) ? L2 : 0.2f * L2;
            float x2 = __expf(L2 - m);
            dsum += x2; sx = fmaf(x2, lo2f(b2), sx); sy = fmaf(x2, hi2f(b2), sy);
        }
    }
#pragma unroll
    for (int o = 32; o; o >>= 1) {
        dsum += __shfl_xor(dsum, o, 64);
        sx   += __shfl_xor(sx, o, 64);
        sy   += __shfl_xor(sy, o, 64);
    }
    const float inv = 1.f / (dsum + 1e-16f);
    if (lane < deg) {
        uint32 ah = (uint32)__half_as_ushort(__float2half(ex * inv));
        e1[begin + lane] = (ev & 0xFFFFu) | (ah << 16);
    }
    for (int j0 = 64; j0 < deg; j0 += 64) {        // recompute tail alphas
        int j = j0 + lane;
        if (j < deg) {
            uint32 e2 = e1[begin + j], b2 = csr_ea[begin + j];
            float L2 = fmaf(hi2f(b2), c1, fmaf(lo2f(b2), c0, ssrc[e2 & 0xFFFFu] + sd));
            L2 = (L2 > 0.f) ? L2 : 0.2f * L2;
            uint32 ah = (uint32)__half_as_ushort(__float2half(__expf(L2 - m) * inv));
            e1[begin + j] = (e2 & 0xFFFFu) | (ah << 16);
        }
    }
    if (lane == 0) SXY[n] = make_float2(sx * inv, sy * inv);
}

// ---------------------------------------------------------------------------
// gather: XCD-sliced weighted row reduction.  blockIdx&7 = channel slice
// (round-robins across XCDs -> each XCD gathers only its 2MB HW slice).
// Wave per node: 8 edges x 8 uint-lanes per iteration.
__global__ __launch_bounds__(256) void gather_kernel(
        const uint32* __restrict__ HWs, const uint32* __restrict__ e1,
        const float2* __restrict__ SXY, const int* __restrict__ row_ptr,
        const float* __restrict__ PAR, int layer, uint32* __restrict__ Hout,
        float* __restrict__ hw5, int wantw5) {
    const int s = blockIdx.x & 7;
    const int n = (blockIdx.x >> 3) * 4 + (threadIdx.x >> 6);
    const int lane = threadIdx.x & 63;
    const int g = lane >> 3, u = lane & 7;
    const int begin = __builtin_amdgcn_readfirstlane(row_ptr[n]);
    const int deg   = __builtin_amdgcn_readfirstlane(row_ptr[n + 1]) - begin;

    const uint32* rowb = HWs + (size_t)s * NV * 8;
    float acc0 = 0.f, acc1 = 0.f;
    for (int j0 = 0; j0 < deg; j0 += 8) {
        int e = j0 + g;
        int ec = (e < deg) ? e : (deg - 1);
        uint32 al = __builtin_nontemporal_load(&e1[begin + ec]);
        float a = (e < deg) ? a2f(al) : 0.f;
        uint32 hv = rowb[(size_t)(al & 0xFFFFu) * 8 + u];
        acc0 = fmaf(a, lo2f(hv), acc0);
        acc1 = fmaf(a, hi2f(hv), acc1);
    }
    // reduce over the 8 edge-groups (xor of lane bits 3..5)
#pragma unroll
    for (int o = 8; o < 64; o <<= 1) {
        acc0 += __shfl_xor(acc0, o, 64);
        acc1 += __shfl_xor(acc1, o, 64);
    }

    const float2 sxy = SXY[n];
    const int ch = s * 16 + u * 2;
    const float* WEl = PAR + P_WE + layer * 256;
    const float* Bl  = PAR + P_BIAS + layer * DD;
    float o0 = acc0 + sxy.x * WEl[ch]     + sxy.y * WEl[DD + ch]     + Bl[ch];
    float o1 = acc1 + sxy.x * WEl[ch + 1] + sxy.y * WEl[DD + ch + 1] + Bl[ch + 1];
    o0 = (o0 > 0.f) ? o0 : 0.01f * o0;
    o1 = (o1 > 0.f) ? o1 : 0.01f * o1;
    if (g == 0)
        __builtin_nontemporal_store(pack2(o0, o1), &Hout[HIDXU(s, n, u)]);

    if (wantw5) {
        float p = (g == 0) ? (o0 * PAR[P_W5 + ch] + o1 * PAR[P_W5 + ch + 1]) : 0.f;
#pragma unroll
        for (int o = 32; o; o >>= 1) p += __shfl_xor(p, o, 64);
        if (lane == 0) atomicAdd(&hw5[n], p);
    }
}

// ---------------------------------------------------------------------------
__global__ __launch_bounds__(256) void final_kernel(
        const float* __restrict__ hw5, const uint32* __restrict__ e1,
        const uint32* __restrict__ csr_ea, const int* __restrict__ row_ptr,
        const float* __restrict__ PAR, const int* __restrict__ FLAG,
        void* __restrict__ out) {
    const int flag = FLAG[0];
    int lane = threadIdx.x & 63;
    int n = blockIdx.x * 4 + (threadIdx.x >> 6);
    int begin = __builtin_amdgcn_readfirstlane(row_ptr[n]);
    int deg   = __builtin_amdgcn_readfirstlane(row_ptr[n + 1]) - begin;
    float c50 = PAR[P_CVEC + 8], c51 = PAR[P_CVEC + 9];
    float ce0 = PAR[P_CVEC + 10], ce1 = PAR[P_CVEC + 11];
    float b5v = PAR[P_SC5], a5s = PAR[P_SC5 + 1];
    float hd = PAR[P_SC5 + 2] * hw5[n];

    float m = -3.4e38f;
    for (int j0 = 0; j0 < deg; j0 += 64) {
        int j = j0 + lane;
        if (j < deg) {
            int s = (int)(e1[begin + j] & 0xFFFFu);
            uint32 eb = csr_ea[begin + j];
            float L = fmaf(hi2f(eb), c51, fmaf(lo2f(eb), c50, fmaf(a5s, hw5[s], hd)));
            L = (L > 0.f) ? L : 0.2f * L;
            m = fmaxf(m, L);
        }
    }
#pragma unroll
    for (int o = 32; o; o >>= 1) m = fmaxf(m, __shfl_xor(m, o, 64));

    float dsum = 0.f, msum = 0.f;
    for (int j0 = 0; j0 < deg; j0 += 64) {
        int j = j0 + lane;
        if (j < deg) {
            int s = (int)(e1[begin + j] & 0xFFFFu);
            uint32 eb = csr_ea[begin + j];
            float hs5 = hw5[s];
            float L = fmaf(hi2f(eb), c51, fmaf(lo2f(eb), c50, fmaf(a5s, hs5, hd)));
            L = (L > 0.f) ? L : 0.2f * L;
            float ex = __expf(L - m);
            dsum += ex;
            msum = fmaf(ex, hs5 + fmaf(hi2f(eb), ce1, lo2f(eb) * ce0), msum);
        }
    }
#pragma unroll
    for (int o = 32; o; o >>= 1) {
        dsum += __shfl_xor(dsum, o, 64);
        msum += __shfl_xor(msum, o, 64);
    }
    if (lane == 0) {
        float r = msum / (dsum + 1e-16f) + b5v;
        if (flag) ((float*)out)[n] = r;
        else      ((u16b*)out)[n] = (u16b)f2bf_bits(r);
    }
}

// ---------------------------------------------------------------------------
extern "C" void kernel_launch(void* const* d_in, const int* in_sizes, int n_in,
                              void* d_out, int out_size, void* d_ws, size_t ws_size,
                              hipStream_t stream) {
    const void* x   = d_in[0];
    const int*  ei  = (const int*)d_in[1];
    const void* ea  = d_in[2];
    const int*  cur = (const int*)d_in[3];
    const void* vge = d_in[4];
    const void* vnd = d_in[5];
    const void* pW  = d_in[6];
    const void* pb  = d_in[7];
    const void* Ws  = d_in[8];
    const void* bs  = d_in[9];
    const void* asr = d_in[10];
    const void* ads = d_in[11];
    const void* aeg = d_in[12];
    const void* Wes = d_in[13];
    const void* W5  = d_in[14];
    const void* b5  = d_in[15];
    const void* as5 = d_in[16];
    const void* ad5 = d_in[17];
    const void* ae5 = d_in[18];
    const void* We5 = d_in[19];
    (void)in_sizes; (void)n_in; (void)out_size;

    const int* e_src = ei;
    const int* e_dst = ei + EE;

    size_t off = 0;
    char* base = (char*)d_ws;
    auto carve = [&](size_t bytes) {
        void* p = base + off;
        off += (bytes + 255) & ~(size_t)255;
        return p;
    };
    int*    FLAG   = (int*)carve(256);
    float*  PAR    = (float*)carve((size_t)P_TOT * 4);
    u16b*   WB     = (u16b*)carve(4 * DD * DD * 2);
    uint32* H0     = (uint32*)carve((size_t)NV * DD * 2);
    uint32* H1     = (uint32*)carve((size_t)NV * DD * 2); // also bucket storage
    float*  SS     = (float*)carve(NV * 4);
    float*  SD     = (float*)carve(NV * 4);
    float*  HW5v   = (float*)carve(NV * 4);
    float2* SXY    = (float2*)carve((size_t)NV * 8);
    int*    COUNTS = (int*)carve(65536 * 4);
    int*    ROWPTR = (int*)carve(65536 * 4);
    int*    GCUR   = (int*)carve(256 * 4);
    int*    PART   = (int*)carve(256 * 4);
    int*    BOFF   = (int*)carve(256 * 4);
    uint32* E1     = (uint32*)carve((size_t)EE * 4);   // src u16 | alpha fp16
    uint32* CSREA  = (uint32*)carve((size_t)EE * 4);
    size_t need = off;

    uint32* BUKX = H1;
    uint32* BUKY = H1 + (size_t)NBUK * BCAP;

    sniff_kernel<<<1, 256, 0, stream>>>((const unsigned short*)ea, FLAG);

    if (need > ws_size) {
        zero_out_kernel<<<(NV + 255) / 256, 256, 0, stream>>>(
            d_out, FLAG, (float)(ws_size >> 20));
        return;
    }

    prep_kernel<<<5, 256, 0, stream>>>(Wes, aeg, We5, ae5, asr, ads, bs,
                                       W5, b5, as5, ad5, FLAG, PAR);
    prepack_kernel<<<32, 256, 0, stream>>>(Ws, FLAG, WB);
    proj_kernel<<<NV / 4, 256, 0, stream>>>(x, pW, pb, cur, vge, vnd, FLAG, H0);

    init_kernel<<<2, 256, 0, stream>>>(GCUR, COUNTS);
    bucketize_kernel<<<EE / 4096, 256, 0, stream>>>(e_src, e_dst, ea, FLAG,
                                                    GCUR, BUKX, BUKY);
    bcount_kernel<<<NBUK, 256, 0, stream>>>(BUKX, GCUR, COUNTS);
    scan1_kernel<<<63, 256, 0, stream>>>(COUNTS, ROWPTR, PART);
    scan2_kernel<<<1, 64, 0, stream>>>(PART, BOFF, 63);
    scan3_kernel<<<63, 256, 0, stream>>>(ROWPTR, BOFF);
    bscatter_kernel<<<NBUK, 256, 0, stream>>>(BUKX, BUKY, GCUR, ROWPTR,
                                              E1, CSREA);
    hipMemsetAsync(HW5v, 0, (size_t)NV * 4, stream);

    for (int l = 0; l < 4; ++l) {
        gemm_kernel<<<NV / 64, 256, 0, stream>>>(
            H0, WB + (size_t)l * 16384, PAR + l * DD, H1, SS, SD);
        attn_kernel<<<NV / 4, 256, 0, stream>>>(
            SS, SD, E1, CSREA, ROWPTR, PAR, l, SXY);
        gather_kernel<<<(NV / 4) * 8, 256, 0, stream>>>(
            H1, E1, SXY, ROWPTR, PAR, l, H0, HW5v, (l == 3) ? 1 : 0);
    }

    final_kernel<<<NV / 4, 256, 0, stream>>>(HW5v, E1, CSREA, ROWPTR, PAR,
                                             FLAG, d_out);
}

// Round 10
// 1112.235 us; speedup vs baseline: 1.0908x; 1.0908x over previous
//
#include <hip/hip_runtime.h>
#include <hip/hip_bf16.h>
#include <hip/hip_fp16.h>

// Problem constants (fixed by the reference).
#define BB   128
#define NN   500
#define NV   64000        // BB*NN nodes
#define EE   1048576      // edges
#define DD   128
#define FIN  5
#define VNN  10
#define NBUK 250          // dst>>8 buckets (250*256 = 64000)
#define BCAP 8192         // bucket capacity (expected 4194, >50 sigma margin)

typedef unsigned int   uint32;
typedef unsigned short u16b;
typedef __attribute__((ext_vector_type(8))) short short8;   // 8 bf16 (4 VGPRs)
typedef __attribute__((ext_vector_type(4))) float float4v;  // MFMA C/D

// fp32 param-block layout (element offsets)
#define P_ASRC  0          // 4*128
#define P_ADST  512        // 4*128
#define P_WE    1024       // 4*2*128
#define P_BIAS  2048       // 4*128
#define P_W5    2560       // 128
#define P_CVEC  2688       // 12
#define P_SC5   2700       // b5, as5, ad5
#define P_TOT   2816

// slice-major H layout: H[s][n][u], s in [0,8) 16-ch slices, u in [0,8) uint
#define HIDXU(s, n, u) (((size_t)(s) * NV + (n)) * 8 + (u))

static __device__ __forceinline__ float bf2f(__hip_bfloat16 v) { return __bfloat162float(v); }
static __device__ __forceinline__ float lo2f(uint32 u) { return __uint_as_float(u << 16); }
static __device__ __forceinline__ float hi2f(uint32 u) { return __uint_as_float(u & 0xFFFF0000u); }
static __device__ __forceinline__ uint32 f2bf_bits(float f) {
    uint32 u = __float_as_uint(f);
    return (u + 0x7FFFu + ((u >> 16) & 1u)) >> 16;
}
static __device__ __forceinline__ uint32 pack2(float a, float b) {
    return (f2bf_bits(a) & 0xFFFFu) | (f2bf_bits(b) << 16);
}
static __device__ __forceinline__ float ldf(const void* p, int i, int flag) {
    return flag ? ((const float*)p)[i] : bf2f(((const __hip_bfloat16*)p)[i]);
}
static __device__ __forceinline__ float a2f(uint32 al) {
    return __half2float(__ushort_as_half((unsigned short)(al >> 16)));
}

// ---------------------------------------------------------------------------
__global__ void sniff_kernel(const unsigned short* __restrict__ p16, int* __restrict__ FLAG) {
    __shared__ int sHigh, sZero;
    if (threadIdx.x == 0) { sHigh = 0; sZero = 0; }
    __syncthreads();
    unsigned short v = p16[2 * threadIdx.x];
    if (v >= 0x8000u) atomicOr(&sHigh, 1);
    if (v == 0)       atomicAdd(&sZero, 1);
    __syncthreads();
    if (threadIdx.x == 0) FLAG[0] = (sHigh || sZero >= 128) ? 1 : 0;
}

__global__ void zero_out_kernel(void* __restrict__ out, const int* __restrict__ FLAG, float tag) {
    int i = blockIdx.x * blockDim.x + threadIdx.x;
    if (i >= NV) return;
    float v = (i == 0) ? tag : 0.f;
    if (FLAG[0]) ((float*)out)[i] = v;
    else         ((u16b*)out)[i] = (u16b)f2bf_bits(v);
}

// ---------------------------------------------------------------------------
__global__ void prep_kernel(const void* __restrict__ Wes, const void* __restrict__ aeg,
                            const void* __restrict__ We5, const void* __restrict__ ae5,
                            const void* __restrict__ asr, const void* __restrict__ ads,
                            const void* __restrict__ bs, const void* __restrict__ W5,
                            const void* __restrict__ b5, const void* __restrict__ as5,
                            const void* __restrict__ ad5, const int* __restrict__ FLAG,
                            float* __restrict__ PAR) {
    const int flag = FLAG[0];
    if (blockIdx.x == 0) {
        for (int i = threadIdx.x; i < 512; i += 256) PAR[P_ASRC + i] = ldf(asr, i, flag);
    } else if (blockIdx.x == 1) {
        for (int i = threadIdx.x; i < 512; i += 256) PAR[P_ADST + i] = ldf(ads, i, flag);
    } else if (blockIdx.x == 2) {
        for (int i = threadIdx.x; i < 1024; i += 256) PAR[P_WE + i] = ldf(Wes, i, flag);
    } else if (blockIdx.x == 3) {
        for (int i = threadIdx.x; i < 512; i += 256) PAR[P_BIAS + i] = ldf(bs, i, flag);
    } else if (blockIdx.x == 4) {
        int tid = threadIdx.x;
        if (tid < 128) {
            PAR[P_W5 + tid] = ldf(W5, tid, flag);
        } else if (tid < 136) {
            int l = (tid - 128) >> 1, r = (tid - 128) & 1;
            float s = 0.f;
            for (int ch = 0; ch < DD; ++ch)
                s += ldf(Wes, l * 256 + r * DD + ch, flag) * ldf(aeg, l * DD + ch, flag);
            PAR[P_CVEC + l * 2 + r] = s;
        } else if (tid == 136) {
            float ae = ldf(ae5, 0, flag);
            float w0 = ldf(We5, 0, flag), w1 = ldf(We5, 1, flag);
            PAR[P_CVEC + 8] = w0 * ae; PAR[P_CVEC + 9] = w1 * ae;
            PAR[P_CVEC + 10] = w0;     PAR[P_CVEC + 11] = w1;
            PAR[P_SC5 + 0] = ldf(b5, 0, flag);
            PAR[P_SC5 + 1] = ldf(as5, 0, flag);
            PAR[P_SC5 + 2] = ldf(ad5, 0, flag);
        }
    }
}

// ---------------------------------------------------------------------------
// prepack W into MFMA B-fragment layout.
__global__ __launch_bounds__(256) void prepack_kernel(const void* __restrict__ Ws,
                                                      const int* __restrict__ FLAG,
                                                      u16b* __restrict__ WB) {
    const int flag = FLAG[0];
    int t = blockIdx.x * 256 + threadIdx.x;
    int lane = t & 63;
    int frag = t >> 6;
    int nchunk = frag & 7, kblk = (frag >> 3) & 3, l = frag >> 5;
    int n = nchunk * 16 + (lane & 15);
    int kbase = kblk * 32 + (lane >> 4) * 8;
#pragma unroll
    for (int j = 0; j < 8; ++j) {
        int idx = l * 16384 + (kbase + j) * 128 + n;
        u16b bits = flag ? (u16b)f2bf_bits(((const float*)Ws)[idx])
                         : ((const u16b*)Ws)[idx];
        WB[(size_t)t * 8 + j] = bits;
    }
}

// ---------------------------------------------------------------------------
// input projection -> slice-major H0
__global__ __launch_bounds__(256) void proj_kernel(
        const void* __restrict__ x, const void* __restrict__ pW,
        const void* __restrict__ pb, const int* __restrict__ curr,
        const void* __restrict__ vge, const void* __restrict__ vnd,
        const int* __restrict__ FLAG, uint32* __restrict__ H) {
    const int flag = FLAG[0];
    const int n = blockIdx.x * 4 + (threadIdx.x >> 6);
    const int lane = threadIdx.x & 63;
    const int b = n / NN;
    int cv = curr[b]; if ((unsigned)cv >= VNN) cv = 0;
    float xv[FIN];
#pragma unroll
    for (int k = 0; k < FIN; ++k) xv[k] = ldf(x, n * FIN + k, flag);
    const int ch = lane * 2;
    float s0 = ldf(pb, ch, flag), s1 = ldf(pb, ch + 1, flag);
#pragma unroll
    for (int k = 0; k < FIN; ++k) {
        s0 = fmaf(xv[k], ldf(pW, k * DD + ch, flag), s0);
        s1 = fmaf(xv[k], ldf(pW, k * DD + ch + 1, flag), s1);
    }
    s0 = (s0 > 0.f) ? s0 : 0.01f * s0;
    s1 = (s1 > 0.f) ? s1 : 0.01f * s1;
    s0 += ldf(vge, b * DD + ch, flag) + ldf(vnd, (b * VNN + cv) * DD + ch, flag);
    s1 += ldf(vge, b * DD + ch + 1, flag) + ldf(vnd, (b * VNN + cv) * DD + ch + 1, flag);
    H[HIDXU(lane >> 3, n, lane & 7)] = pack2(s0, s1);
}

// ---------------------------------------------------------------------------
// CSR build (2-level bucket sort), E1 = {src u16 | alpha fp16<<16} SoA.
__global__ void init_kernel(int* __restrict__ gcur, int* __restrict__ counts) {
    int t = blockIdx.x * 256 + threadIdx.x;
    if (t < NBUK) gcur[t] = t * BCAP;
    if (t < 512) counts[NV + t] = 0;
}

__global__ __launch_bounds__(256) void bucketize_kernel(
        const int* __restrict__ src, const int* __restrict__ dst,
        const void* __restrict__ eaP, const int* __restrict__ FLAG,
        int* __restrict__ gcur, uint32* __restrict__ bukx, uint32* __restrict__ buky) {
    __shared__ int cnt[256];
    __shared__ int cur[256];
    const int flag = FLAG[0];
    const int t = threadIdx.x;
    const int e0 = blockIdx.x * 4096;
    cnt[t] = 0;
    __syncthreads();
    int d[16];
#pragma unroll
    for (int i = 0; i < 16; ++i) {
        d[i] = dst[e0 + i * 256 + t];
        if ((unsigned)d[i] >= NV) d[i] = -1;
        if (d[i] >= 0) atomicAdd(&cnt[d[i] >> 8], 1);
    }
    __syncthreads();
    if (t < NBUK) {
        int c = cnt[t];
        cur[t] = c ? atomicAdd(&gcur[t], c) : 0;
    }
    __syncthreads();
#pragma unroll
    for (int i = 0; i < 16; ++i) {
        if (d[i] < 0) continue;
        int e = e0 + i * 256 + t;
        int b = d[i] >> 8;
        int s = src[e];
        if ((unsigned)s >= NV) s = 0;
        uint32 eb;
        if (flag) { float2 v = ((const float2*)eaP)[e]; eb = pack2(v.x, v.y); }
        else      eb = ((const uint32*)eaP)[e];
        int p = atomicAdd(&cur[b], 1);
        if (p < (b + 1) * BCAP) {
            bukx[p] = (uint32)((s & 0xFFFF) | ((d[i] & 255) << 16));
            buky[p] = eb;
        }
    }
}

__global__ __launch_bounds__(256) void bcount_kernel(
        const uint32* __restrict__ bukx, const int* __restrict__ gcur,
        int* __restrict__ counts) {
    __shared__ int c[256];
    const int b = blockIdx.x, t = threadIdx.x;
    c[t] = 0;
    __syncthreads();
    const int base = b * BCAP;
    int cnt = gcur[b] - base;
    if (cnt > BCAP) cnt = BCAP;
    for (int i = t; i < cnt; i += 256)
        atomicAdd(&c[(bukx[base + i] >> 16) & 255], 1);
    __syncthreads();
    counts[b * 256 + t] = c[t];
}

__global__ __launch_bounds__(256) void scan1_kernel(const int* __restrict__ counts,
                                                    int* __restrict__ row_ptr,
                                                    int* __restrict__ partials) {
    __shared__ int sdata[256];
    int tid = threadIdx.x;
    int4 v = ((const int4*)counts)[blockIdx.x * 256 + tid];
    int sum = v.x + v.y + v.z + v.w;
    sdata[tid] = sum;
    __syncthreads();
    int acc = sum;
    for (int off = 1; off < 256; off <<= 1) {
        int t = (tid >= off) ? sdata[tid - off] : 0;
        __syncthreads();
        acc += t;
        sdata[tid] = acc;
        __syncthreads();
    }
    int excl = acc - sum;
    int base = blockIdx.x * 1024 + tid * 4;
    int run = excl;
    if (base + 0 <= NV) row_ptr[base + 0] = run; run += v.x;
    if (base + 1 <= NV) row_ptr[base + 1] = run; run += v.y;
    if (base + 2 <= NV) row_ptr[base + 2] = run; run += v.z;
    if (base + 3 <= NV) row_ptr[base + 3] = run;
    if (tid == 255) partials[blockIdx.x] = acc;
}

__global__ __launch_bounds__(64) void scan2_kernel(const int* __restrict__ partials,
                                                   int* __restrict__ boff, int nb) {
    int lane = threadIdx.x;
    int v = (lane < nb) ? partials[lane] : 0;
    int orig = v;
#pragma unroll
    for (int off = 1; off < 64; off <<= 1) {
        int t = __shfl_up(v, off, 64);
        if (lane >= off) v += t;
    }
    boff[lane] = v - orig;
}

__global__ __launch_bounds__(256) void scan3_kernel(int* __restrict__ row_ptr,
                                                    const int* __restrict__ boff) {
    int add = boff[blockIdx.x];
    int base = blockIdx.x * 1024 + threadIdx.x * 4;
#pragma unroll
    for (int j = 0; j < 4; ++j) {
        int i = base + j;
        if (i <= NV) row_ptr[i] += add;
    }
}

__global__ __launch_bounds__(256) void bscatter_kernel(
        const uint32* __restrict__ bukx, const uint32* __restrict__ buky,
        const int* __restrict__ gcur, const int* __restrict__ row_ptr,
        uint32* __restrict__ e1, uint32* __restrict__ csr_ea) {
    __shared__ int cur[256];
    const int b = blockIdx.x, t = threadIdx.x;
    cur[t] = row_ptr[b * 256 + t];
    __syncthreads();
    const int base = b * BCAP;
    int cnt = gcur[b] - base;
    if (cnt > BCAP) cnt = BCAP;
    for (int i = t; i < cnt; i += 256) {
        uint32 x = bukx[base + i];
        uint32 y = buky[base + i];
        int p = atomicAdd(&cur[(x >> 16) & 255], 1);
        e1[p] = x & 0xFFFFu;
        csr_ea[p] = y;
    }
}

// ---------------------------------------------------------------------------
// MFMA GEMM over slice-major H: HW = H @ W + fused attention dots.
__global__ __launch_bounds__(256) void gemm_kernel(
        const uint32* __restrict__ Hu, const u16b* __restrict__ WBl,
        const float* __restrict__ PARl, uint32* __restrict__ HWu,
        float* __restrict__ ssrc, float* __restrict__ sdst) {
    __shared__ float hs[64 * 129];
    __shared__ float pp[512];
    const int tid = threadIdx.x;
    const int lane = tid & 63;
    const int wave = tid >> 6;
    const int quad = lane >> 4;
    const int n0 = blockIdx.x * 64;
    const int m = n0 + wave * 16 + (lane & 15);

    const int sA = quad >> 1, uA = (quad & 1) * 4;
    short8 a0 = *(const short8*)(Hu + HIDXU(0 + sA, m, uA));
    short8 a1 = *(const short8*)(Hu + HIDXU(2 + sA, m, uA));
    short8 a2 = *(const short8*)(Hu + HIDXU(4 + sA, m, uA));
    short8 a3 = *(const short8*)(Hu + HIDXU(6 + sA, m, uA));

#pragma unroll
    for (int nt = 0; nt < 8; ++nt) {
        const u16b* bbase = WBl + ((size_t)nt * 512 + lane * 8);
        short8 b0 = *(const short8*)(bbase + 0 * 4096);
        short8 b1 = *(const short8*)(bbase + 1 * 4096);
        short8 b2 = *(const short8*)(bbase + 2 * 4096);
        short8 b3 = *(const short8*)(bbase + 3 * 4096);
        float4v acc = {0.f, 0.f, 0.f, 0.f};
        acc = __builtin_amdgcn_mfma_f32_16x16x32_bf16(a0, b0, acc, 0, 0, 0);
        acc = __builtin_amdgcn_mfma_f32_16x16x32_bf16(a1, b1, acc, 0, 0, 0);
        acc = __builtin_amdgcn_mfma_f32_16x16x32_bf16(a2, b2, acc, 0, 0, 0);
        acc = __builtin_amdgcn_mfma_f32_16x16x32_bf16(a3, b3, acc, 0, 0, 0);
#pragma unroll
        for (int r = 0; r < 4; ++r)
            hs[(wave * 16 + quad * 4 + r) * 129 + nt * 16 + (lane & 15)] = acc[r];
    }
    __syncthreads();

    {
        const int mn = tid & 63, cg = tid >> 6;
        const float* Asr = PARl + P_ASRC;
        const float* Ads = PARl + P_ADST;
        const float* row = hs + mn * 129 + cg * 32;
        float ps = 0.f, pd = 0.f;
#pragma unroll
        for (int j = 0; j < 32; ++j) {
            float v = row[j];
            ps = fmaf(v, Asr[cg * 32 + j], ps);
            pd = fmaf(v, Ads[cg * 32 + j], pd);
        }
        pp[tid] = ps; pp[256 + tid] = pd;
    }
    __syncthreads();
    if (tid < 64) {
        ssrc[n0 + tid] = pp[tid] + pp[64 + tid] + pp[128 + tid] + pp[192 + tid];
        sdst[n0 + tid] = pp[256 + tid] + pp[320 + tid] + pp[384 + tid] + pp[448 + tid];
    }

#pragma unroll
    for (int it = 0; it < 16; ++it) {
        int f = it * 256 + tid;
        int u = f & 7, n = (f >> 3) & 63, s = f >> 9;
        const float* p = hs + n * 129 + s * 16 + u * 2;
        HWu[HIDXU(s, n0 + n, u)] = pack2(p[0], p[1]);
    }
}

// ---------------------------------------------------------------------------
// attn: per-node softmax; writes alpha (fp16) into E1 high16 and
// (sx*inv, sy*inv) into SXY. One wave per node.
__global__ __launch_bounds__(256) void attn_kernel(
        const float* __restrict__ ssrc, const float* __restrict__ sdst,
        uint32* __restrict__ e1, const uint32* __restrict__ csr_ea,
        const int* __restrict__ row_ptr, const float* __restrict__ PAR,
        int layer, float2* __restrict__ SXY) {
    const int lane = threadIdx.x & 63;
    const int n = blockIdx.x * 4 + (threadIdx.x >> 6);
    const int begin = __builtin_amdgcn_readfirstlane(row_ptr[n]);
    const int deg   = __builtin_amdgcn_readfirstlane(row_ptr[n + 1]) - begin;
    const float c0 = PAR[P_CVEC + 2 * layer], c1 = PAR[P_CVEC + 2 * layer + 1];
    const float sd = sdst[n];

    uint32 ev = 0, eb = 0;
    float L = -3.4e38f;
    if (lane < deg) {
        ev = e1[begin + lane];
        eb = csr_ea[begin + lane];
        L = fmaf(hi2f(eb), c1, fmaf(lo2f(eb), c0, ssrc[ev & 0xFFFFu] + sd));
        L = (L > 0.f) ? L : 0.2f * L;
    }
    float m = L;
    for (int j0 = 64; j0 < deg; j0 += 64) {        // essentially never
        int j = j0 + lane;
        if (j < deg) {
            uint32 e2 = e1[begin + j], b2 = csr_ea[begin + j];
            float L2 = fmaf(hi2f(b2), c1, fmaf(lo2f(b2), c0, ssrc[e2 & 0xFFFFu] + sd));
            L2 = (L2 > 0.f) ? L2 : 0.2f * L2;
            m = fmaxf(m, L2);
        }
    }
#pragma unroll
    for (int o = 32; o; o >>= 1) m = fmaxf(m, __shfl_xor(m, o, 64));

    float ex = (lane < deg) ? __expf(L - m) : 0.f;
    float dsum = ex, sx = ex * lo2f(eb), sy = ex * hi2f(eb);
    for (int j0 = 64; j0 < deg; j0 += 64) {
        int j = j0 + lane;
        if (j < deg) {
            uint32 e2 = e1[begin + j], b2 = csr_ea[begin + j];
            float L2 = fmaf(hi2f(b2), c1, fmaf(lo2f(b2), c0, ssrc[e2 & 0xFFFFu] + sd));
            L2 = (L2 > 0.f) ? L2 : 0.2f * L2;
            float x2 = __expf(L2 - m);
            dsum += x2; sx = fmaf(x2, lo2f(b2), sx); sy = fmaf(x2, hi2f(b2), sy);
        }
    }
#pragma unroll
    for (int o = 32; o; o >>= 1) {
        dsum += __shfl_xor(dsum, o, 64);
        sx   += __shfl_xor(sx, o, 64);
        sy   += __shfl_xor(sy, o, 64);
    }
    const float inv = 1.f / (dsum + 1e-16f);
    if (lane < deg) {
        uint32 ah = (uint32)__half_as_ushort(__float2half(ex * inv));
        e1[begin + lane] = (ev & 0xFFFFu) | (ah << 16);
    }
    for (int j0 = 64; j0 < deg; j0 += 64) {        // recompute tail alphas
        int j = j0 + lane;
        if (j < deg) {
            uint32 e2 = e1[begin + j], b2 = csr_ea[begin + j];
            float L2 = fmaf(hi2f(b2), c1, fmaf(lo2f(b2), c0, ssrc[e2 & 0xFFFFu] + sd));
            L2 = (L2 > 0.f) ? L2 : 0.2f * L2;
            uint32 ah = (uint32)__half_as_ushort(__float2half(__expf(L2 - m) * inv));
            e1[begin + j] = (e2 & 0xFFFFu) | (ah << 16);
        }
    }
    if (lane == 0) SXY[n] = make_float2(sx * inv, sy * inv);
}

// ---------------------------------------------------------------------------
// gather: XCD-sliced weighted row reduction with restored MLP.
// blockIdx&7 = channel slice (round-robins across XCDs -> per-XCD 2MB
// L2-resident row slice, confirmed by R8 FETCH drop). Wave per (node,slice):
// one coalesced NT metadata load -> shuffle-derived addresses -> up to 8
// independent row loads in flight (issue loop / consume loop split).
__global__ __launch_bounds__(256) void gather_kernel(
        const uint32* __restrict__ HWs, const uint32* __restrict__ e1,
        const float2* __restrict__ SXY, const int* __restrict__ row_ptr,
        const float* __restrict__ PAR, int layer, uint32* __restrict__ Hout,
        float* __restrict__ hw5, int wantw5) {
    const int s = blockIdx.x & 7;
    const int n = (blockIdx.x >> 3) * 4 + (threadIdx.x >> 6);
    const int lane = threadIdx.x & 63;
    const int g = lane >> 3, u = lane & 7;
    const int begin = __builtin_amdgcn_readfirstlane(row_ptr[n]);
    const int deg   = __builtin_amdgcn_readfirstlane(row_ptr[n + 1]) - begin;
    const int dmain = (deg < 64) ? deg : 64;
    const int nit   = (dmain + 7) >> 3;            // wave-uniform, 0..8

    // metadata for up to 64 edges: one coalesced NT load into lane regs
    uint32 ev = 0;
    if (lane < dmain) ev = __builtin_nontemporal_load(&e1[begin + lane]);

    const uint32* rowb = HWs + (size_t)s * NV * 8;

    // issue loop: all row loads in flight before consumption
    uint32 hv[8]; float av[8];
#pragma unroll
    for (int q = 0; q < 8; ++q) {
        if (q < nit) {
            int e = q * 8 + g;
            uint32 al = __shfl(ev, e, 64);
            av[q] = (e < dmain) ? a2f(al) : 0.f;
            hv[q] = rowb[(size_t)(al & 0xFFFFu) * 8 + u];
        } else { av[q] = 0.f; hv[q] = 0; }
    }
    float acc0 = 0.f, acc1 = 0.f;
#pragma unroll
    for (int q = 0; q < 8; ++q) {
        acc0 = fmaf(av[q], lo2f(hv[q]), acc0);
        acc1 = fmaf(av[q], hi2f(hv[q]), acc1);
    }
    for (int jj = 64; jj < deg; jj += 8) {         // essentially never
        int e = jj + g;
        int ec = (e < deg) ? e : (deg - 1);
        uint32 al = e1[begin + ec];
        float a = (e < deg) ? a2f(al) : 0.f;
        uint32 hb = rowb[(size_t)(al & 0xFFFFu) * 8 + u];
        acc0 = fmaf(a, lo2f(hb), acc0);
        acc1 = fmaf(a, hi2f(hb), acc1);
    }
    // reduce over the 8 edge-groups
#pragma unroll
    for (int o = 8; o < 64; o <<= 1) {
        acc0 += __shfl_xor(acc0, o, 64);
        acc1 += __shfl_xor(acc1, o, 64);
    }

    const float2 sxy = SXY[n];
    const int ch = s * 16 + u * 2;
    const float* WEl = PAR + P_WE + layer * 256;
    const float* Bl  = PAR + P_BIAS + layer * DD;
    float o0 = acc0 + sxy.x * WEl[ch]     + sxy.y * WEl[DD + ch]     + Bl[ch];
    float o1 = acc1 + sxy.x * WEl[ch + 1] + sxy.y * WEl[DD + ch + 1] + Bl[ch + 1];
    o0 = (o0 > 0.f) ? o0 : 0.01f * o0;
    o1 = (o1 > 0.f) ? o1 : 0.01f * o1;
    if (g == 0)
        Hout[HIDXU(s, n, u)] = pack2(o0, o1);       // cached store (no NT)

    if (wantw5) {
        float p = (g == 0) ? (o0 * PAR[P_W5 + ch] + o1 * PAR[P_W5 + ch + 1]) : 0.f;
#pragma unroll
        for (int o = 32; o; o >>= 1) p += __shfl_xor(p, o, 64);
        if (lane == 0) atomicAdd(&hw5[n], p);
    }
}

// ---------------------------------------------------------------------------
__global__ __launch_bounds__(256) void final_kernel(
        const float* __restrict__ hw5, const uint32* __restrict__ e1,
        const uint32* __restrict__ csr_ea, const int* __restrict__ row_ptr,
        const float* __restrict__ PAR, const int* __restrict__ FLAG,
        void* __restrict__ out) {
    const int flag = FLAG[0];
    int lane = threadIdx.x & 63;
    int n = blockIdx.x * 4 + (threadIdx.x >> 6);
    int begin = __builtin_amdgcn_readfirstlane(row_ptr[n]);
    int deg   = __builtin_amdgcn_readfirstlane(row_ptr[n + 1]) - begin;
    float c50 = PAR[P_CVEC + 8], c51 = PAR[P_CVEC + 9];
    float ce0 = PAR[P_CVEC + 10], ce1 = PAR[P_CVEC + 11];
    float b5v = PAR[P_SC5], a5s = PAR[P_SC5 + 1];
    float hd = PAR[P_SC5 + 2] * hw5[n];

    float m = -3.4e38f;
    for (int j0 = 0; j0 < deg; j0 += 64) {
        int j = j0 + lane;
        if (j < deg) {
            int s = (int)(e1[begin + j] & 0xFFFFu);
            uint32 eb = csr_ea[begin + j];
            float L = fmaf(hi2f(eb), c51, fmaf(lo2f(eb), c50, fmaf(a5s, hw5[s], hd)));
            L = (L > 0.f) ? L : 0.2f * L;
            m = fmaxf(m, L);
        }
    }
#pragma unroll
    for (int o = 32; o; o >>= 1) m = fmaxf(m, __shfl_xor(m, o, 64));

    float dsum = 0.f, msum = 0.f;
    for (int j0 = 0; j0 < deg; j0 += 64) {
        int j = j0 + lane;
        if (j < deg) {
            int s = (int)(e1[begin + j] & 0xFFFFu);
            uint32 eb = csr_ea[begin + j];
            float hs5 = hw5[s];
            float L = fmaf(hi2f(eb), c51, fmaf(lo2f(eb), c50, fmaf(a5s, hs5, hd)));
            L = (L > 0.f) ? L : 0.2f * L;
            float ex = __expf(L - m);
            dsum += ex;
            msum = fmaf(ex, hs5 + fmaf(hi2f(eb), ce1, lo2f(eb) * ce0), msum);
        }
    }
#pragma unroll
    for (int o = 32; o; o >>= 1) {
        dsum += __shfl_xor(dsum, o, 64);
        msum += __shfl_xor(msum, o, 64);
    }
    if (lane == 0) {
        float r = msum / (dsum + 1e-16f) + b5v;
        if (flag) ((float*)out)[n] = r;
        else      ((u16b*)out)[n] = (u16b)f2bf_bits(r);
    }
}

// ---------------------------------------------------------------------------
extern "C" void kernel_launch(void* const* d_in, const int* in_sizes, int n_in,
                              void* d_out, int out_size, void* d_ws, size_t ws_size,
                              hipStream_t stream) {
    const void* x   = d_in[0];
    const int*  ei  = (const int*)d_in[1];
    const void* ea  = d_in[2];
    const int*  cur = (const int*)d_in[3];
    const void* vge = d_in[4];
    const void* vnd = d_in[5];
    const void* pW  = d_in[6];
    const void* pb  = d_in[7];
    const void* Ws  = d_in[8];
    const void* bs  = d_in[9];
    const void* asr = d_in[10];
    const void* ads = d_in[11];
    const void* aeg = d_in[12];
    const void* Wes = d_in[13];
    const void* W5  = d_in[14];
    const void* b5  = d_in[15];
    const void* as5 = d_in[16];
    const void* ad5 = d_in[17];
    const void* ae5 = d_in[18];
    const void* We5 = d_in[19];
    (void)in_sizes; (void)n_in; (void)out_size;

    const int* e_src = ei;
    const int* e_dst = ei + EE;

    size_t off = 0;
    char* base = (char*)d_ws;
    auto carve = [&](size_t bytes) {
        void* p = base + off;
        off += (bytes + 255) & ~(size_t)255;
        return p;
    };
    int*    FLAG   = (int*)carve(256);
    float*  PAR    = (float*)carve((size_t)P_TOT * 4);
    u16b*   WB     = (u16b*)carve(4 * DD * DD * 2);
    uint32* H0     = (uint32*)carve((size_t)NV * DD * 2);
    uint32* H1     = (uint32*)carve((size_t)NV * DD * 2); // also bucket storage
    float*  SS     = (float*)carve(NV * 4);
    float*  SD     = (float*)carve(NV * 4);
    float*  HW5v   = (float*)carve(NV * 4);
    float2* SXY    = (float2*)carve((size_t)NV * 8);
    int*    COUNTS = (int*)carve(65536 * 4);
    int*    ROWPTR = (int*)carve(65536 * 4);
    int*    GCUR   = (int*)carve(256 * 4);
    int*    PART   = (int*)carve(256 * 4);
    int*    BOFF   = (int*)carve(256 * 4);
    uint32* E1     = (uint32*)carve((size_t)EE * 4);   // src u16 | alpha fp16
    uint32* CSREA  = (uint32*)carve((size_t)EE * 4);
    size_t need = off;

    uint32* BUKX = H1;
    uint32* BUKY = H1 + (size_t)NBUK * BCAP;

    sniff_kernel<<<1, 256, 0, stream>>>((const unsigned short*)ea, FLAG);

    if (need > ws_size) {
        zero_out_kernel<<<(NV + 255) / 256, 256, 0, stream>>>(
            d_out, FLAG, (float)(ws_size >> 20));
        return;
    }

    prep_kernel<<<5, 256, 0, stream>>>(Wes, aeg, We5, ae5, asr, ads, bs,
                                       W5, b5, as5, ad5, FLAG, PAR);
    prepack_kernel<<<32, 256, 0, stream>>>(Ws, FLAG, WB);
    proj_kernel<<<NV / 4, 256, 0, stream>>>(x, pW, pb, cur, vge, vnd, FLAG, H0);

    init_kernel<<<2, 256, 0, stream>>>(GCUR, COUNTS);
    bucketize_kernel<<<EE / 4096, 256, 0, stream>>>(e_src, e_dst, ea, FLAG,
                                                    GCUR, BUKX, BUKY);
    bcount_kernel<<<NBUK, 256, 0, stream>>>(BUKX, GCUR, COUNTS);
    scan1_kernel<<<63, 256, 0, stream>>>(COUNTS, ROWPTR, PART);
    scan2_kernel<<<1, 64, 0, stream>>>(PART, BOFF, 63);
    scan3_kernel<<<63, 256, 0, stream>>>(ROWPTR, BOFF);
    bscatter_kernel<<<NBUK, 256, 0, stream>>>(BUKX, BUKY, GCUR, ROWPTR,
                                              E1, CSREA);
    (void)hipMemsetAsync(HW5v, 0, (size_t)NV * 4, stream);

    for (int l = 0; l < 4; ++l) {
        gemm_kernel<<<NV / 64, 256, 0, stream>>>(
            H0, WB + (size_t)l * 16384, PAR + l * DD, H1, SS, SD);
        attn_kernel<<<NV / 4, 256, 0, stream>>>(
            SS, SD, E1, CSREA, ROWPTR, PAR, l, SXY);
        gather_kernel<<<(NV / 4) * 8, 256, 0, stream>>>(
            H1, E1, SXY, ROWPTR, PAR, l, H0, HW5v, (l == 3) ? 1 : 0);
    }

    final_kernel<<<NV / 4, 256, 0, stream>>>(HW5v, E1, CSREA, ROWPTR, PAR,
                                             FLAG, d_out);
}

// Round 11
// 775.698 us; speedup vs baseline: 1.5641x; 1.4339x over previous
//
#include <hip/hip_runtime.h>
#include <hip/hip_bf16.h>
#include <hip/hip_fp16.h>

// Problem constants (fixed by the reference).
#define BB   128
#define NN   500
#define NV   64000        // BB*NN nodes
#define EE   1048576      // edges
#define DD   128
#define FIN  5
#define VNN  10
#define NBUK 250          // dst>>8 buckets (250*256 = 64000)
#define BCAP 8192         // bucket capacity (expected 4194, >50 sigma margin)

typedef unsigned int   uint32;
typedef unsigned short u16b;
typedef __attribute__((ext_vector_type(8))) short short8;   // 8 bf16 (4 VGPRs)
typedef __attribute__((ext_vector_type(4))) float float4v;  // MFMA C/D

// fp32 param-block layout (element offsets)
#define P_ASRC  0          // 4*128
#define P_ADST  512        // 4*128
#define P_WE    1024       // 4*2*128
#define P_BIAS  2048       // 4*128
#define P_W5    2560       // 128
#define P_CVEC  2688       // 12
#define P_SC5   2700       // b5, as5, ad5
#define P_TOT   2816

// slice-major H layout: H[s][n][u], s in [0,8) 16-ch slices, u in [0,8) uint
#define HIDXU(s, n, u) (((size_t)(s) * NV + (n)) * 8 + (u))

static __device__ __forceinline__ float bf2f(__hip_bfloat16 v) { return __bfloat162float(v); }
static __device__ __forceinline__ float lo2f(uint32 u) { return __uint_as_float(u << 16); }
static __device__ __forceinline__ float hi2f(uint32 u) { return __uint_as_float(u & 0xFFFF0000u); }
static __device__ __forceinline__ uint32 f2bf_bits(float f) {
    uint32 u = __float_as_uint(f);
    return (u + 0x7FFFu + ((u >> 16) & 1u)) >> 16;
}
static __device__ __forceinline__ uint32 pack2(float a, float b) {
    return (f2bf_bits(a) & 0xFFFFu) | (f2bf_bits(b) << 16);
}
static __device__ __forceinline__ float ldf(const void* p, int i, int flag) {
    return flag ? ((const float*)p)[i] : bf2f(((const __hip_bfloat16*)p)[i]);
}
static __device__ __forceinline__ float a2f(uint32 al) {
    return __half2float(__ushort_as_half((unsigned short)(al >> 16)));
}

// ---------------------------------------------------------------------------
__global__ void sniff_kernel(const unsigned short* __restrict__ p16, int* __restrict__ FLAG) {
    __shared__ int sHigh, sZero;
    if (threadIdx.x == 0) { sHigh = 0; sZero = 0; }
    __syncthreads();
    unsigned short v = p16[2 * threadIdx.x];
    if (v >= 0x8000u) atomicOr(&sHigh, 1);
    if (v == 0)       atomicAdd(&sZero, 1);
    __syncthreads();
    if (threadIdx.x == 0) FLAG[0] = (sHigh || sZero >= 128) ? 1 : 0;
}

__global__ void zero_out_kernel(void* __restrict__ out, const int* __restrict__ FLAG, float tag) {
    int i = blockIdx.x * blockDim.x + threadIdx.x;
    if (i >= NV) return;
    float v = (i == 0) ? tag : 0.f;
    if (FLAG[0]) ((float*)out)[i] = v;
    else         ((u16b*)out)[i] = (u16b)f2bf_bits(v);
}

// ---------------------------------------------------------------------------
__global__ void prep_kernel(const void* __restrict__ Wes, const void* __restrict__ aeg,
                            const void* __restrict__ We5, const void* __restrict__ ae5,
                            const void* __restrict__ asr, const void* __restrict__ ads,
                            const void* __restrict__ bs, const void* __restrict__ W5,
                            const void* __restrict__ b5, const void* __restrict__ as5,
                            const void* __restrict__ ad5, const int* __restrict__ FLAG,
                            float* __restrict__ PAR) {
    const int flag = FLAG[0];
    if (blockIdx.x == 0) {
        for (int i = threadIdx.x; i < 512; i += 256) PAR[P_ASRC + i] = ldf(asr, i, flag);
    } else if (blockIdx.x == 1) {
        for (int i = threadIdx.x; i < 512; i += 256) PAR[P_ADST + i] = ldf(ads, i, flag);
    } else if (blockIdx.x == 2) {
        for (int i = threadIdx.x; i < 1024; i += 256) PAR[P_WE + i] = ldf(Wes, i, flag);
    } else if (blockIdx.x == 3) {
        for (int i = threadIdx.x; i < 512; i += 256) PAR[P_BIAS + i] = ldf(bs, i, flag);
    } else if (blockIdx.x == 4) {
        int tid = threadIdx.x;
        if (tid < 128) {
            PAR[P_W5 + tid] = ldf(W5, tid, flag);
        } else if (tid < 136) {
            int l = (tid - 128) >> 1, r = (tid - 128) & 1;
            float s = 0.f;
            for (int ch = 0; ch < DD; ++ch)
                s += ldf(Wes, l * 256 + r * DD + ch, flag) * ldf(aeg, l * DD + ch, flag);
            PAR[P_CVEC + l * 2 + r] = s;
        } else if (tid == 136) {
            float ae = ldf(ae5, 0, flag);
            float w0 = ldf(We5, 0, flag), w1 = ldf(We5, 1, flag);
            PAR[P_CVEC + 8] = w0 * ae; PAR[P_CVEC + 9] = w1 * ae;
            PAR[P_CVEC + 10] = w0;     PAR[P_CVEC + 11] = w1;
            PAR[P_SC5 + 0] = ldf(b5, 0, flag);
            PAR[P_SC5 + 1] = ldf(as5, 0, flag);
            PAR[P_SC5 + 2] = ldf(ad5, 0, flag);
        }
    }
}

// ---------------------------------------------------------------------------
// prepack W into MFMA B-fragment layout.
__global__ __launch_bounds__(256) void prepack_kernel(const void* __restrict__ Ws,
                                                      const int* __restrict__ FLAG,
                                                      u16b* __restrict__ WB) {
    const int flag = FLAG[0];
    int t = blockIdx.x * 256 + threadIdx.x;
    int lane = t & 63;
    int frag = t >> 6;
    int nchunk = frag & 7, kblk = (frag >> 3) & 3, l = frag >> 5;
    int n = nchunk * 16 + (lane & 15);
    int kbase = kblk * 32 + (lane >> 4) * 8;
#pragma unroll
    for (int j = 0; j < 8; ++j) {
        int idx = l * 16384 + (kbase + j) * 128 + n;
        u16b bits = flag ? (u16b)f2bf_bits(((const float*)Ws)[idx])
                         : ((const u16b*)Ws)[idx];
        WB[(size_t)t * 8 + j] = bits;
    }
}

// ---------------------------------------------------------------------------
// input projection -> slice-major H0
__global__ __launch_bounds__(256) void proj_kernel(
        const void* __restrict__ x, const void* __restrict__ pW,
        const void* __restrict__ pb, const int* __restrict__ curr,
        const void* __restrict__ vge, const void* __restrict__ vnd,
        const int* __restrict__ FLAG, uint32* __restrict__ H) {
    const int flag = FLAG[0];
    const int n = blockIdx.x * 4 + (threadIdx.x >> 6);
    const int lane = threadIdx.x & 63;
    const int b = n / NN;
    int cv = curr[b]; if ((unsigned)cv >= VNN) cv = 0;
    float xv[FIN];
#pragma unroll
    for (int k = 0; k < FIN; ++k) xv[k] = ldf(x, n * FIN + k, flag);
    const int ch = lane * 2;
    float s0 = ldf(pb, ch, flag), s1 = ldf(pb, ch + 1, flag);
#pragma unroll
    for (int k = 0; k < FIN; ++k) {
        s0 = fmaf(xv[k], ldf(pW, k * DD + ch, flag), s0);
        s1 = fmaf(xv[k], ldf(pW, k * DD + ch + 1, flag), s1);
    }
    s0 = (s0 > 0.f) ? s0 : 0.01f * s0;
    s1 = (s1 > 0.f) ? s1 : 0.01f * s1;
    s0 += ldf(vge, b * DD + ch, flag) + ldf(vnd, (b * VNN + cv) * DD + ch, flag);
    s1 += ldf(vge, b * DD + ch + 1, flag) + ldf(vnd, (b * VNN + cv) * DD + ch + 1, flag);
    H[HIDXU(lane >> 3, n, lane & 7)] = pack2(s0, s1);
}

// ---------------------------------------------------------------------------
// CSR build (2-level bucket sort), E1 = {src u16 | alpha fp16<<16} SoA.
__global__ void init_kernel(int* __restrict__ gcur, int* __restrict__ counts) {
    int t = blockIdx.x * 256 + threadIdx.x;
    if (t < NBUK) gcur[t] = t * BCAP;
    if (t < 512) counts[NV + t] = 0;
}

__global__ __launch_bounds__(256) void bucketize_kernel(
        const int* __restrict__ src, const int* __restrict__ dst,
        const void* __restrict__ eaP, const int* __restrict__ FLAG,
        int* __restrict__ gcur, uint32* __restrict__ bukx, uint32* __restrict__ buky) {
    __shared__ int cnt[256];
    __shared__ int cur[256];
    const int flag = FLAG[0];
    const int t = threadIdx.x;
    const int e0 = blockIdx.x * 4096;
    cnt[t] = 0;
    __syncthreads();
    int d[16];
#pragma unroll
    for (int i = 0; i < 16; ++i) {
        d[i] = dst[e0 + i * 256 + t];
        if ((unsigned)d[i] >= NV) d[i] = -1;
        if (d[i] >= 0) atomicAdd(&cnt[d[i] >> 8], 1);
    }
    __syncthreads();
    if (t < NBUK) {
        int c = cnt[t];
        cur[t] = c ? atomicAdd(&gcur[t], c) : 0;
    }
    __syncthreads();
#pragma unroll
    for (int i = 0; i < 16; ++i) {
        if (d[i] < 0) continue;
        int e = e0 + i * 256 + t;
        int b = d[i] >> 8;
        int s = src[e];
        if ((unsigned)s >= NV) s = 0;
        uint32 eb;
        if (flag) { float2 v = ((const float2*)eaP)[e]; eb = pack2(v.x, v.y); }
        else      eb = ((const uint32*)eaP)[e];
        int p = atomicAdd(&cur[b], 1);
        if (p < (b + 1) * BCAP) {
            bukx[p] = (uint32)((s & 0xFFFF) | ((d[i] & 255) << 16));
            buky[p] = eb;
        }
    }
}

__global__ __launch_bounds__(256) void bcount_kernel(
        const uint32* __restrict__ bukx, const int* __restrict__ gcur,
        int* __restrict__ counts) {
    __shared__ int c[256];
    const int b = blockIdx.x, t = threadIdx.x;
    c[t] = 0;
    __syncthreads();
    const int base = b * BCAP;
    int cnt = gcur[b] - base;
    if (cnt > BCAP) cnt = BCAP;
    for (int i = t; i < cnt; i += 256)
        atomicAdd(&c[(bukx[base + i] >> 16) & 255], 1);
    __syncthreads();
    counts[b * 256 + t] = c[t];
}

__global__ __launch_bounds__(256) void scan1_kernel(const int* __restrict__ counts,
                                                    int* __restrict__ row_ptr,
                                                    int* __restrict__ partials) {
    __shared__ int sdata[256];
    int tid = threadIdx.x;
    int4 v = ((const int4*)counts)[blockIdx.x * 256 + tid];
    int sum = v.x + v.y + v.z + v.w;
    sdata[tid] = sum;
    __syncthreads();
    int acc = sum;
    for (int off = 1; off < 256; off <<= 1) {
        int t = (tid >= off) ? sdata[tid - off] : 0;
        __syncthreads();
        acc += t;
        sdata[tid] = acc;
        __syncthreads();
    }
    int excl = acc - sum;
    int base = blockIdx.x * 1024 + tid * 4;
    int run = excl;
    if (base + 0 <= NV) row_ptr[base + 0] = run; run += v.x;
    if (base + 1 <= NV) row_ptr[base + 1] = run; run += v.y;
    if (base + 2 <= NV) row_ptr[base + 2] = run; run += v.z;
    if (base + 3 <= NV) row_ptr[base + 3] = run;
    if (tid == 255) partials[blockIdx.x] = acc;
}

__global__ __launch_bounds__(64) void scan2_kernel(const int* __restrict__ partials,
                                                   int* __restrict__ boff, int nb) {
    int lane = threadIdx.x;
    int v = (lane < nb) ? partials[lane] : 0;
    int orig = v;
#pragma unroll
    for (int off = 1; off < 64; off <<= 1) {
        int t = __shfl_up(v, off, 64);
        if (lane >= off) v += t;
    }
    boff[lane] = v - orig;
}

__global__ __launch_bounds__(256) void scan3_kernel(int* __restrict__ row_ptr,
                                                    const int* __restrict__ boff) {
    int add = boff[blockIdx.x];
    int base = blockIdx.x * 1024 + threadIdx.x * 4;
#pragma unroll
    for (int j = 0; j < 4; ++j) {
        int i = base + j;
        if (i <= NV) row_ptr[i] += add;
    }
}

__global__ __launch_bounds__(256) void bscatter_kernel(
        const uint32* __restrict__ bukx, const uint32* __restrict__ buky,
        const int* __restrict__ gcur, const int* __restrict__ row_ptr,
        uint32* __restrict__ e1, uint32* __restrict__ csr_ea) {
    __shared__ int cur[256];
    const int b = blockIdx.x, t = threadIdx.x;
    cur[t] = row_ptr[b * 256 + t];
    __syncthreads();
    const int base = b * BCAP;
    int cnt = gcur[b] - base;
    if (cnt > BCAP) cnt = BCAP;
    for (int i = t; i < cnt; i += 256) {
        uint32 x = bukx[base + i];
        uint32 y = buky[base + i];
        int p = atomicAdd(&cur[(x >> 16) & 255], 1);
        e1[p] = x & 0xFFFFu;
        csr_ea[p] = y;
    }
}

// ---------------------------------------------------------------------------
// MFMA GEMM over slice-major H: HW = H @ W + fused attention dots.
__global__ __launch_bounds__(256) void gemm_kernel(
        const uint32* __restrict__ Hu, const u16b* __restrict__ WBl,
        const float* __restrict__ PARl, uint32* __restrict__ HWu,
        float* __restrict__ ssrc, float* __restrict__ sdst) {
    __shared__ float hs[64 * 129];
    __shared__ float pp[512];
    const int tid = threadIdx.x;
    const int lane = tid & 63;
    const int wave = tid >> 6;
    const int quad = lane >> 4;
    const int n0 = blockIdx.x * 64;
    const int m = n0 + wave * 16 + (lane & 15);

    const int sA = quad >> 1, uA = (quad & 1) * 4;
    short8 a0 = *(const short8*)(Hu + HIDXU(0 + sA, m, uA));
    short8 a1 = *(const short8*)(Hu + HIDXU(2 + sA, m, uA));
    short8 a2 = *(const short8*)(Hu + HIDXU(4 + sA, m, uA));
    short8 a3 = *(const short8*)(Hu + HIDXU(6 + sA, m, uA));

#pragma unroll
    for (int nt = 0; nt < 8; ++nt) {
        const u16b* bbase = WBl + ((size_t)nt * 512 + lane * 8);
        short8 b0 = *(const short8*)(bbase + 0 * 4096);
        short8 b1 = *(const short8*)(bbase + 1 * 4096);
        short8 b2 = *(const short8*)(bbase + 2 * 4096);
        short8 b3 = *(const short8*)(bbase + 3 * 4096);
        float4v acc = {0.f, 0.f, 0.f, 0.f};
        acc = __builtin_amdgcn_mfma_f32_16x16x32_bf16(a0, b0, acc, 0, 0, 0);
        acc = __builtin_amdgcn_mfma_f32_16x16x32_bf16(a1, b1, acc, 0, 0, 0);
        acc = __builtin_amdgcn_mfma_f32_16x16x32_bf16(a2, b2, acc, 0, 0, 0);
        acc = __builtin_amdgcn_mfma_f32_16x16x32_bf16(a3, b3, acc, 0, 0, 0);
#pragma unroll
        for (int r = 0; r < 4; ++r)
            hs[(wave * 16 + quad * 4 + r) * 129 + nt * 16 + (lane & 15)] = acc[r];
    }
    __syncthreads();

    {
        const int mn = tid & 63, cg = tid >> 6;
        const float* Asr = PARl + P_ASRC;
        const float* Ads = PARl + P_ADST;
        const float* row = hs + mn * 129 + cg * 32;
        float ps = 0.f, pd = 0.f;
#pragma unroll
        for (int j = 0; j < 32; ++j) {
            float v = row[j];
            ps = fmaf(v, Asr[cg * 32 + j], ps);
            pd = fmaf(v, Ads[cg * 32 + j], pd);
        }
        pp[tid] = ps; pp[256 + tid] = pd;
    }
    __syncthreads();
    if (tid < 64) {
        ssrc[n0 + tid] = pp[tid] + pp[64 + tid] + pp[128 + tid] + pp[192 + tid];
        sdst[n0 + tid] = pp[256 + tid] + pp[320 + tid] + pp[384 + tid] + pp[448 + tid];
    }

#pragma unroll
    for (int it = 0; it < 16; ++it) {
        int f = it * 256 + tid;
        int u = f & 7, n = (f >> 3) & 63, s = f >> 9;
        const float* p = hs + n * 129 + s * 16 + u * 2;
        HWu[HIDXU(s, n0 + n, u)] = pack2(p[0], p[1]);
    }
}

// ---------------------------------------------------------------------------
// attn: per-node softmax; writes alpha (fp16) into E1 high16 and
// (sx*inv, sy*inv) into SXY. One wave per node.
__global__ __launch_bounds__(256) void attn_kernel(
        const float* __restrict__ ssrc, const float* __restrict__ sdst,
        uint32* __restrict__ e1, const uint32* __restrict__ csr_ea,
        const int* __restrict__ row_ptr, const float* __restrict__ PAR,
        int layer, float2* __restrict__ SXY) {
    const int lane = threadIdx.x & 63;
    const int n = blockIdx.x * 4 + (threadIdx.x >> 6);
    const int begin = __builtin_amdgcn_readfirstlane(row_ptr[n]);
    const int deg   = __builtin_amdgcn_readfirstlane(row_ptr[n + 1]) - begin;
    const float c0 = PAR[P_CVEC + 2 * layer], c1 = PAR[P_CVEC + 2 * layer + 1];
    const float sd = sdst[n];

    uint32 ev = 0, eb = 0;
    float L = -3.4e38f;
    if (lane < deg) {
        ev = e1[begin + lane];
        eb = csr_ea[begin + lane];
        L = fmaf(hi2f(eb), c1, fmaf(lo2f(eb), c0, ssrc[ev & 0xFFFFu] + sd));
        L = (L > 0.f) ? L : 0.2f * L;
    }
    float m = L;
    for (int j0 = 64; j0 < deg; j0 += 64) {        // essentially never
        int j = j0 + lane;
        if (j < deg) {
            uint32 e2 = e1[begin + j], b2 = csr_ea[begin + j];
            float L2 = fmaf(hi2f(b2), c1, fmaf(lo2f(b2), c0, ssrc[e2 & 0xFFFFu] + sd));
            L2 = (L2 > 0.f) ? L2 : 0.2f * L2;
            m = fmaxf(m, L2);
        }
    }
#pragma unroll
    for (int o = 32; o; o >>= 1) m = fmaxf(m, __shfl_xor(m, o, 64));

    float ex = (lane < deg) ? __expf(L - m) : 0.f;
    float dsum = ex, sx = ex * lo2f(eb), sy = ex * hi2f(eb);
    for (int j0 = 64; j0 < deg; j0 += 64) {
        int j = j0 + lane;
        if (j < deg) {
            uint32 e2 = e1[begin + j], b2 = csr_ea[begin + j];
            float L2 = fmaf(hi2f(b2), c1, fmaf(lo2f(b2), c0, ssrc[e2 & 0xFFFFu] + sd));
            L2 = (L2 > 0.f) ? L2 : 0.2f * L2;
            float x2 = __expf(L2 - m);
            dsum += x2; sx = fmaf(x2, lo2f(b2), sx); sy = fmaf(x2, hi2f(b2), sy);
        }
    }
#pragma unroll
    for (int o = 32; o; o >>= 1) {
        dsum += __shfl_xor(dsum, o, 64);
        sx   += __shfl_xor(sx, o, 64);
        sy   += __shfl_xor(sy, o, 64);
    }
    const float inv = 1.f / (dsum + 1e-16f);
    if (lane < deg) {
        uint32 ah = (uint32)__half_as_ushort(__float2half(ex * inv));
        e1[begin + lane] = (ev & 0xFFFFu) | (ah << 16);
    }
    for (int j0 = 64; j0 < deg; j0 += 64) {        // recompute tail alphas
        int j = j0 + lane;
        if (j < deg) {
            uint32 e2 = e1[begin + j], b2 = csr_ea[begin + j];
            float L2 = fmaf(hi2f(b2), c1, fmaf(lo2f(b2), c0, ssrc[e2 & 0xFFFFu] + sd));
            L2 = (L2 > 0.f) ? L2 : 0.2f * L2;
            uint32 ah = (uint32)__half_as_ushort(__float2half(__expf(L2 - m) * inv));
            e1[begin + j] = (e2 & 0xFFFFu) | (ah << 16);
        }
    }
    if (lane == 0) SXY[n] = make_float2(sx * inv, sy * inv);
}

// ---------------------------------------------------------------------------
// gather v3: XCD-sliced + block-amortized metadata staging.
// Block = 16 consecutive nodes x 1 slice (blockIdx&7 = slice = XCD).
// Phase 1: cooperative coalesced NT burst of the block's contiguous E1
// range (CSR-sorted) + row_ptr + SXY + param slice into LDS -> metadata
// HBM latency paid once per block, not once per wave.
// Phase 2: wave handles 4 nodes; deg<=32 fast path fully unrolled ->
// 16 independent L2-resident row loads in flight per wave.
__global__ __launch_bounds__(256) void gather_kernel(
        const uint32* __restrict__ HWs, const uint32* __restrict__ e1,
        const float2* __restrict__ SXY, const int* __restrict__ row_ptr,
        const float* __restrict__ PAR, int layer, uint32* __restrict__ Hout,
        float* __restrict__ hw5, int wantw5) {
    __shared__ int rp[17];
    __shared__ float2 sxyS[16];
    __shared__ float wesA[16], wesB[16], blS[16], w5S[16];
    __shared__ uint32 meta[2048];
    const int s = blockIdx.x & 7;
    const int n0 = (blockIdx.x >> 3) * 16;
    const int tid = threadIdx.x;

    if (tid <= 16) rp[tid] = row_ptr[n0 + tid];
    if (tid >= 64 && tid < 80) sxyS[tid - 64] = SXY[n0 + tid - 64];
    if (tid >= 96 && tid < 112) {
        int q = tid - 96, ch = s * 16 + q;
        wesA[q] = PAR[P_WE + layer * 256 + ch];
        wesB[q] = PAR[P_WE + layer * 256 + DD + ch];
        blS[q]  = PAR[P_BIAS + layer * DD + ch];
        w5S[q]  = PAR[P_W5 + ch];
    }
    __syncthreads();
    const int ebase = rp[0];
    const int ecount = rp[16] - ebase;
    const int ovf = (ecount > 2048);               // never in practice
    {
        int stage = ovf ? 2048 : ecount;
        for (int i = tid; i < stage; i += 256)
            meta[i] = __builtin_nontemporal_load(&e1[ebase + i]);
    }
    __syncthreads();

    const int wave = tid >> 6, lane = tid & 63;
    const int g = lane >> 3, u = lane & 7;
    const uint32* rowb = HWs + (size_t)s * NV * 8;

#pragma unroll
    for (int w4 = 0; w4 < 4; ++w4) {
        const int nn = wave * 4 + w4;
        const int begin = rp[nn] - ebase;
        const int deg = rp[nn + 1] - rp[nn];
        float acc0 = 0.f, acc1 = 0.f;
        if (!ovf && deg <= 32) {
            // fast path: <=4 groups of 8, fully unrolled; all loads in flight
#pragma unroll
            for (int q = 0; q < 4; ++q) {
                int e = q * 8 + g;
                uint32 al = (e < deg) ? meta[begin + e] : 0u;
                uint32 hv = rowb[(size_t)(al & 0xFFFFu) * 8 + u];
                float a = (e < deg) ? a2f(al) : 0.f;
                acc0 = fmaf(a, lo2f(hv), acc0);
                acc1 = fmaf(a, hi2f(hv), acc1);
            }
        } else {                                    // rare
            for (int j0 = 0; j0 < deg; j0 += 8) {
                int e = j0 + g;
                if (e < deg) {
                    uint32 al = e1[ebase + begin + e];
                    uint32 hv = rowb[(size_t)(al & 0xFFFFu) * 8 + u];
                    float a = a2f(al);
                    acc0 = fmaf(a, lo2f(hv), acc0);
                    acc1 = fmaf(a, hi2f(hv), acc1);
                }
            }
        }
#pragma unroll
        for (int o = 8; o < 64; o <<= 1) {
            acc0 += __shfl_xor(acc0, o, 64);
            acc1 += __shfl_xor(acc1, o, 64);
        }

        const float2 sxy = sxyS[nn];
        const int c2 = u * 2;
        float o0 = acc0 + sxy.x * wesA[c2]     + sxy.y * wesB[c2]     + blS[c2];
        float o1 = acc1 + sxy.x * wesA[c2 + 1] + sxy.y * wesB[c2 + 1] + blS[c2 + 1];
        o0 = (o0 > 0.f) ? o0 : 0.01f * o0;
        o1 = (o1 > 0.f) ? o1 : 0.01f * o1;
        if (g == 0)
            Hout[HIDXU(s, n0 + nn, u)] = pack2(o0, o1);

        if (wantw5) {
            float p = (g == 0) ? (o0 * w5S[c2] + o1 * w5S[c2 + 1]) : 0.f;
#pragma unroll
            for (int o = 32; o; o >>= 1) p += __shfl_xor(p, o, 64);
            if (lane == 0) atomicAdd(&hw5[n0 + nn], p);
        }
    }
}

// ---------------------------------------------------------------------------
__global__ __launch_bounds__(256) void final_kernel(
        const float* __restrict__ hw5, const uint32* __restrict__ e1,
        const uint32* __restrict__ csr_ea, const int* __restrict__ row_ptr,
        const float* __restrict__ PAR, const int* __restrict__ FLAG,
        void* __restrict__ out) {
    const int flag = FLAG[0];
    int lane = threadIdx.x & 63;
    int n = blockIdx.x * 4 + (threadIdx.x >> 6);
    int begin = __builtin_amdgcn_readfirstlane(row_ptr[n]);
    int deg   = __builtin_amdgcn_readfirstlane(row_ptr[n + 1]) - begin;
    float c50 = PAR[P_CVEC + 8], c51 = PAR[P_CVEC + 9];
    float ce0 = PAR[P_CVEC + 10], ce1 = PAR[P_CVEC + 11];
    float b5v = PAR[P_SC5], a5s = PAR[P_SC5 + 1];
    float hd = PAR[P_SC5 + 2] * hw5[n];

    float m = -3.4e38f;
    for (int j0 = 0; j0 < deg; j0 += 64) {
        int j = j0 + lane;
        if (j < deg) {
            int s = (int)(e1[begin + j] & 0xFFFFu);
            uint32 eb = csr_ea[begin + j];
            float L = fmaf(hi2f(eb), c51, fmaf(lo2f(eb), c50, fmaf(a5s, hw5[s], hd)));
            L = (L > 0.f) ? L : 0.2f * L;
            m = fmaxf(m, L);
        }
    }
#pragma unroll
    for (int o = 32; o; o >>= 1) m = fmaxf(m, __shfl_xor(m, o, 64));

    float dsum = 0.f, msum = 0.f;
    for (int j0 = 0; j0 < deg; j0 += 64) {
        int j = j0 + lane;
        if (j < deg) {
            int s = (int)(e1[begin + j] & 0xFFFFu);
            uint32 eb = csr_ea[begin + j];
            float hs5 = hw5[s];
            float L = fmaf(hi2f(eb), c51, fmaf(lo2f(eb), c50, fmaf(a5s, hs5, hd)));
            L = (L > 0.f) ? L : 0.2f * L;
            float ex = __expf(L - m);
            dsum += ex;
            msum = fmaf(ex, hs5 + fmaf(hi2f(eb), ce1, lo2f(eb) * ce0), msum);
        }
    }
#pragma unroll
    for (int o = 32; o; o >>= 1) {
        dsum += __shfl_xor(dsum, o, 64);
        msum += __shfl_xor(msum, o, 64);
    }
    if (lane == 0) {
        float r = msum / (dsum + 1e-16f) + b5v;
        if (flag) ((float*)out)[n] = r;
        else      ((u16b*)out)[n] = (u16b)f2bf_bits(r);
    }
}

// ---------------------------------------------------------------------------
extern "C" void kernel_launch(void* const* d_in, const int* in_sizes, int n_in,
                              void* d_out, int out_size, void* d_ws, size_t ws_size,
                              hipStream_t stream) {
    const void* x   = d_in[0];
    const int*  ei  = (const int*)d_in[1];
    const void* ea  = d_in[2];
    const int*  cur = (const int*)d_in[3];
    const void* vge = d_in[4];
    const void* vnd = d_in[5];
    const void* pW  = d_in[6];
    const void* pb  = d_in[7];
    const void* Ws  = d_in[8];
    const void* bs  = d_in[9];
    const void* asr = d_in[10];
    const void* ads = d_in[11];
    const void* aeg = d_in[12];
    const void* Wes = d_in[13];
    const void* W5  = d_in[14];
    const void* b5  = d_in[15];
    const void* as5 = d_in[16];
    const void* ad5 = d_in[17];
    const void* ae5 = d_in[18];
    const void* We5 = d_in[19];
    (void)in_sizes; (void)n_in; (void)out_size;

    const int* e_src = ei;
    const int* e_dst = ei + EE;

    size_t off = 0;
    char* base = (char*)d_ws;
    auto carve = [&](size_t bytes) {
        void* p = base + off;
        off += (bytes + 255) & ~(size_t)255;
        return p;
    };
    int*    FLAG   = (int*)carve(256);
    float*  PAR    = (float*)carve((size_t)P_TOT * 4);
    u16b*   WB     = (u16b*)carve(4 * DD * DD * 2);
    uint32* H0     = (uint32*)carve((size_t)NV * DD * 2);
    uint32* H1     = (uint32*)carve((size_t)NV * DD * 2); // also bucket storage
    float*  SS     = (float*)carve(NV * 4);
    float*  SD     = (float*)carve(NV * 4);
    float*  HW5v   = (float*)carve(NV * 4);
    float2* SXY    = (float2*)carve((size_t)NV * 8);
    int*    COUNTS = (int*)carve(65536 * 4);
    int*    ROWPTR = (int*)carve(65536 * 4);
    int*    GCUR   = (int*)carve(256 * 4);
    int*    PART   = (int*)carve(256 * 4);
    int*    BOFF   = (int*)carve(256 * 4);
    uint32* E1     = (uint32*)carve((size_t)EE * 4);   // src u16 | alpha fp16
    uint32* CSREA  = (uint32*)carve((size_t)EE * 4);
    size_t need = off;

    uint32* BUKX = H1;
    uint32* BUKY = H1 + (size_t)NBUK * BCAP;

    sniff_kernel<<<1, 256, 0, stream>>>((const unsigned short*)ea, FLAG);

    if (need > ws_size) {
        zero_out_kernel<<<(NV + 255) / 256, 256, 0, stream>>>(
            d_out, FLAG, (float)(ws_size >> 20));
        return;
    }

    prep_kernel<<<5, 256, 0, stream>>>(Wes, aeg, We5, ae5, asr, ads, bs,
                                       W5, b5, as5, ad5, FLAG, PAR);
    prepack_kernel<<<32, 256, 0, stream>>>(Ws, FLAG, WB);
    proj_kernel<<<NV / 4, 256, 0, stream>>>(x, pW, pb, cur, vge, vnd, FLAG, H0);

    init_kernel<<<2, 256, 0, stream>>>(GCUR, COUNTS);
    bucketize_kernel<<<EE / 4096, 256, 0, stream>>>(e_src, e_dst, ea, FLAG,
                                                    GCUR, BUKX, BUKY);
    bcount_kernel<<<NBUK, 256, 0, stream>>>(BUKX, GCUR, COUNTS);
    scan1_kernel<<<63, 256, 0, stream>>>(COUNTS, ROWPTR, PART);
    scan2_kernel<<<1, 64, 0, stream>>>(PART, BOFF, 63);
    scan3_kernel<<<63, 256, 0, stream>>>(ROWPTR, BOFF);
    bscatter_kernel<<<NBUK, 256, 0, stream>>>(BUKX, BUKY, GCUR, ROWPTR,
                                              E1, CSREA);
    (void)hipMemsetAsync(HW5v, 0, (size_t)NV * 4, stream);

    for (int l = 0; l < 4; ++l) {
        gemm_kernel<<<NV / 64, 256, 0, stream>>>(
            H0, WB + (size_t)l * 16384, PAR + l * DD, H1, SS, SD);
        attn_kernel<<<NV / 4, 256, 0, stream>>>(
            SS, SD, E1, CSREA, ROWPTR, PAR, l, SXY);
        gather_kernel<<<(NV / 16) * 8, 256, 0, stream>>>(
            H1, E1, SXY, ROWPTR, PAR, l, H0, HW5v, (l == 3) ? 1 : 0);
    }

    final_kernel<<<NV / 4, 256, 0, stream>>>(HW5v, E1, CSREA, ROWPTR, PAR,
                                             FLAG, d_out);
}

// Round 12
// 476.294 us; speedup vs baseline: 2.5473x; 1.6286x over previous
//
#include <hip/hip_runtime.h>
#include <hip/hip_bf16.h>

// Problem constants (fixed by the reference).
#define BB   128
#define NN   500
#define NV   64000        // BB*NN nodes
#define EE   1048576      // edges
#define DD   128
#define FIN  5
#define VNN  10
#define NBUK 250          // dst>>8 buckets (250*256 = 64000)
#define BCAP 8192         // bucket capacity (expected 4194, >50 sigma margin)

typedef unsigned int   uint32;
typedef unsigned short u16b;
typedef __attribute__((ext_vector_type(8))) short short8;   // 8 bf16 (4 VGPRs)
typedef __attribute__((ext_vector_type(4))) float float4v;  // MFMA C/D

// fp32 param-block layout (element offsets)
#define P_ASRC  0          // 4*128
#define P_ADST  512        // 4*128
#define P_WE    1024       // 4*2*128
#define P_BIAS  2048       // 4*128
#define P_W5    2560       // 128
#define P_CVEC  2688       // 12
#define P_SC5   2700       // b5, as5, ad5
#define P_TOT   2816

static __device__ __forceinline__ float bf2f(__hip_bfloat16 v) { return __bfloat162float(v); }
static __device__ __forceinline__ float lo2f(uint32 u) { return __uint_as_float(u << 16); }
static __device__ __forceinline__ float hi2f(uint32 u) { return __uint_as_float(u & 0xFFFF0000u); }
static __device__ __forceinline__ uint32 f2bf_bits(float f) {
    uint32 u = __float_as_uint(f);
    return (u + 0x7FFFu + ((u >> 16) & 1u)) >> 16;
}
static __device__ __forceinline__ uint32 pack2(float a, float b) {
    return (f2bf_bits(a) & 0xFFFFu) | (f2bf_bits(b) << 16);
}
// flag-dispatched loads (cold paths only): 1 -> fp32 container, 0 -> bf16
static __device__ __forceinline__ float ldf(const void* p, int i, int flag) {
    return flag ? ((const float*)p)[i] : bf2f(((const __hip_bfloat16*)p)[i]);
}

// ---------------------------------------------------------------------------
__global__ void sniff_kernel(const unsigned short* __restrict__ p16, int* __restrict__ FLAG) {
    __shared__ int sHigh, sZero;
    if (threadIdx.x == 0) { sHigh = 0; sZero = 0; }
    __syncthreads();
    unsigned short v = p16[2 * threadIdx.x];
    if (v >= 0x8000u) atomicOr(&sHigh, 1);
    if (v == 0)       atomicAdd(&sZero, 1);
    __syncthreads();
    if (threadIdx.x == 0) FLAG[0] = (sHigh || sZero >= 128) ? 1 : 0;
}

__global__ void zero_out_kernel(void* __restrict__ out, const int* __restrict__ FLAG, float tag) {
    int i = blockIdx.x * blockDim.x + threadIdx.x;
    if (i >= NV) return;
    float v = (i == 0) ? tag : 0.f;
    if (FLAG[0]) ((float*)out)[i] = v;
    else         ((u16b*)out)[i] = (u16b)f2bf_bits(v);
}

// ---------------------------------------------------------------------------
__global__ void prep_kernel(const void* __restrict__ Wes, const void* __restrict__ aeg,
                            const void* __restrict__ We5, const void* __restrict__ ae5,
                            const void* __restrict__ asr, const void* __restrict__ ads,
                            const void* __restrict__ bs, const void* __restrict__ W5,
                            const void* __restrict__ b5, const void* __restrict__ as5,
                            const void* __restrict__ ad5, const int* __restrict__ FLAG,
                            float* __restrict__ PAR) {
    const int flag = FLAG[0];
    if (blockIdx.x == 0) {
        for (int i = threadIdx.x; i < 512; i += 256) PAR[P_ASRC + i] = ldf(asr, i, flag);
    } else if (blockIdx.x == 1) {
        for (int i = threadIdx.x; i < 512; i += 256) PAR[P_ADST + i] = ldf(ads, i, flag);
    } else if (blockIdx.x == 2) {
        for (int i = threadIdx.x; i < 1024; i += 256) PAR[P_WE + i] = ldf(Wes, i, flag);
    } else if (blockIdx.x == 3) {
        for (int i = threadIdx.x; i < 512; i += 256) PAR[P_BIAS + i] = ldf(bs, i, flag);
    } else if (blockIdx.x == 4) {
        int tid = threadIdx.x;
        if (tid < 128) {
            PAR[P_W5 + tid] = ldf(W5, tid, flag);
        } else if (tid < 136) {
            int l = (tid - 128) >> 1, r = (tid - 128) & 1;
            float s = 0.f;
            for (int ch = 0; ch < DD; ++ch)
                s += ldf(Wes, l * 256 + r * DD + ch, flag) * ldf(aeg, l * DD + ch, flag);
            PAR[P_CVEC + l * 2 + r] = s;
        } else if (tid == 136) {
            float ae = ldf(ae5, 0, flag);
            float w0 = ldf(We5, 0, flag), w1 = ldf(We5, 1, flag);
            PAR[P_CVEC + 8] = w0 * ae; PAR[P_CVEC + 9] = w1 * ae;
            PAR[P_CVEC + 10] = w0;     PAR[P_CVEC + 11] = w1;
            PAR[P_SC5 + 0] = ldf(b5, 0, flag);
            PAR[P_SC5 + 1] = ldf(as5, 0, flag);
            PAR[P_SC5 + 2] = ldf(ad5, 0, flag);
        }
    }
}

// ---------------------------------------------------------------------------
// prepack W into MFMA B-fragment layout.
__global__ __launch_bounds__(256) void prepack_kernel(const void* __restrict__ Ws,
                                                      const int* __restrict__ FLAG,
                                                      u16b* __restrict__ WB) {
    const int flag = FLAG[0];
    int t = blockIdx.x * 256 + threadIdx.x;
    int lane = t & 63;
    int frag = t >> 6;
    int nchunk = frag & 7, kblk = (frag >> 3) & 3, l = frag >> 5;
    int n = nchunk * 16 + (lane & 15);
    int kbase = kblk * 32 + (lane >> 4) * 8;
#pragma unroll
    for (int j = 0; j < 8; ++j) {
        int idx = l * 16384 + (kbase + j) * 128 + n;
        u16b bits = flag ? (u16b)f2bf_bits(((const float*)Ws)[idx])
                         : ((const u16b*)Ws)[idx];
        WB[(size_t)t * 8 + j] = bits;
    }
}

// ---------------------------------------------------------------------------
// input projection: h0 row-major bf16-packed (64 uints/node)
__global__ __launch_bounds__(256) void proj_kernel(
        const void* __restrict__ x, const void* __restrict__ pW,
        const void* __restrict__ pb, const int* __restrict__ curr,
        const void* __restrict__ vge, const void* __restrict__ vnd,
        const int* __restrict__ FLAG, uint32* __restrict__ H) {
    const int flag = FLAG[0];
    const int n = blockIdx.x * 4 + (threadIdx.x >> 6);
    const int lane = threadIdx.x & 63;
    const int b = n / NN;
    int cv = curr[b]; if ((unsigned)cv >= VNN) cv = 0;
    float xv[FIN];
#pragma unroll
    for (int k = 0; k < FIN; ++k) xv[k] = ldf(x, n * FIN + k, flag);
    const int ch = lane * 2;
    float s0 = ldf(pb, ch, flag), s1 = ldf(pb, ch + 1, flag);
#pragma unroll
    for (int k = 0; k < FIN; ++k) {
        s0 = fmaf(xv[k], ldf(pW, k * DD + ch, flag), s0);
        s1 = fmaf(xv[k], ldf(pW, k * DD + ch + 1, flag), s1);
    }
    s0 = (s0 > 0.f) ? s0 : 0.01f * s0;
    s1 = (s1 > 0.f) ? s1 : 0.01f * s1;
    s0 += ldf(vge, b * DD + ch, flag) + ldf(vnd, (b * VNN + cv) * DD + ch, flag);
    s1 += ldf(vge, b * DD + ch + 1, flag) + ldf(vnd, (b * VNN + cv) * DD + ch + 1, flag);
    H[(size_t)n * 64 + lane] = pack2(s0, s1);
}

// ---------------------------------------------------------------------------
// CSR build (2-level bucket sort)
__global__ void init_kernel(int* __restrict__ gcur, int* __restrict__ counts) {
    int t = blockIdx.x * 256 + threadIdx.x;
    if (t < NBUK) gcur[t] = t * BCAP;
    if (t < 512) counts[NV + t] = 0;
}

__global__ __launch_bounds__(256) void bucketize_kernel(
        const int* __restrict__ src, const int* __restrict__ dst,
        const void* __restrict__ eaP, const int* __restrict__ FLAG,
        int* __restrict__ gcur, uint32* __restrict__ bukx, uint32* __restrict__ buky) {
    __shared__ int cnt[256];
    __shared__ int cur[256];
    const int flag = FLAG[0];
    const int t = threadIdx.x;
    const int e0 = blockIdx.x * 4096;
    cnt[t] = 0;
    __syncthreads();
    int d[16];
#pragma unroll
    for (int i = 0; i < 16; ++i) {
        d[i] = dst[e0 + i * 256 + t];
        if ((unsigned)d[i] >= NV) d[i] = -1;
        if (d[i] >= 0) atomicAdd(&cnt[d[i] >> 8], 1);
    }
    __syncthreads();
    if (t < NBUK) {
        int c = cnt[t];
        cur[t] = c ? atomicAdd(&gcur[t], c) : 0;
    }
    __syncthreads();
#pragma unroll
    for (int i = 0; i < 16; ++i) {
        if (d[i] < 0) continue;
        int e = e0 + i * 256 + t;
        int b = d[i] >> 8;
        int s = src[e];
        if ((unsigned)s >= NV) s = 0;
        uint32 eb;
        if (flag) { float2 v = ((const float2*)eaP)[e]; eb = pack2(v.x, v.y); }
        else      eb = ((const uint32*)eaP)[e];
        int p = atomicAdd(&cur[b], 1);
        if (p < (b + 1) * BCAP) {
            bukx[p] = (uint32)((s & 0xFFFF) | ((d[i] & 255) << 16));
            buky[p] = eb;
        }
    }
}

__global__ __launch_bounds__(256) void bcount_kernel(
        const uint32* __restrict__ bukx, const int* __restrict__ gcur,
        int* __restrict__ counts) {
    __shared__ int c[256];
    const int b = blockIdx.x, t = threadIdx.x;
    c[t] = 0;
    __syncthreads();
    const int base = b * BCAP;
    int cnt = gcur[b] - base;
    if (cnt > BCAP) cnt = BCAP;
    for (int i = t; i < cnt; i += 256)
        atomicAdd(&c[(bukx[base + i] >> 16) & 255], 1);
    __syncthreads();
    counts[b * 256 + t] = c[t];
}

__global__ __launch_bounds__(256) void scan1_kernel(const int* __restrict__ counts,
                                                    int* __restrict__ row_ptr,
                                                    int* __restrict__ partials) {
    __shared__ int sdata[256];
    int tid = threadIdx.x;
    int4 v = ((const int4*)counts)[blockIdx.x * 256 + tid];
    int sum = v.x + v.y + v.z + v.w;
    sdata[tid] = sum;
    __syncthreads();
    int acc = sum;
    for (int off = 1; off < 256; off <<= 1) {
        int t = (tid >= off) ? sdata[tid - off] : 0;
        __syncthreads();
        acc += t;
        sdata[tid] = acc;
        __syncthreads();
    }
    int excl = acc - sum;
    int base = blockIdx.x * 1024 + tid * 4;
    int run = excl;
    if (base + 0 <= NV) row_ptr[base + 0] = run; run += v.x;
    if (base + 1 <= NV) row_ptr[base + 1] = run; run += v.y;
    if (base + 2 <= NV) row_ptr[base + 2] = run; run += v.z;
    if (base + 3 <= NV) row_ptr[base + 3] = run;
    if (tid == 255) partials[blockIdx.x] = acc;
}

__global__ __launch_bounds__(64) void scan2_kernel(const int* __restrict__ partials,
                                                   int* __restrict__ boff, int nb) {
    int lane = threadIdx.x;
    int v = (lane < nb) ? partials[lane] : 0;
    int orig = v;
#pragma unroll
    for (int off = 1; off < 64; off <<= 1) {
        int t = __shfl_up(v, off, 64);
        if (lane >= off) v += t;
    }
    boff[lane] = v - orig;
}

__global__ __launch_bounds__(256) void scan3_kernel(int* __restrict__ row_ptr,
                                                    const int* __restrict__ boff) {
    int add = boff[blockIdx.x];
    int base = blockIdx.x * 1024 + threadIdx.x * 4;
#pragma unroll
    for (int j = 0; j < 4; ++j) {
        int i = base + j;
        if (i <= NV) row_ptr[i] += add;
    }
}

__global__ __launch_bounds__(256) void bscatter_kernel(
        const uint32* __restrict__ bukx, const uint32* __restrict__ buky,
        const int* __restrict__ gcur, const int* __restrict__ row_ptr,
        int* __restrict__ csr_src, uint32* __restrict__ csr_ea) {
    __shared__ int cur[256];
    const int b = blockIdx.x, t = threadIdx.x;
    cur[t] = row_ptr[b * 256 + t];
    __syncthreads();
    const int base = b * BCAP;
    int cnt = gcur[b] - base;
    if (cnt > BCAP) cnt = BCAP;
    for (int i = t; i < cnt; i += 256) {
        uint32 x = bukx[base + i];
        uint32 y = buky[base + i];
        int p = atomicAdd(&cur[(x >> 16) & 255], 1);
        csr_src[p] = (int)(x & 0xFFFFu);
        csr_ea[p] = y;
    }
}

// ---------------------------------------------------------------------------
// MFMA GEMM, full 128 cols per block: HW = H @ W + fused attention dots.
// (R7 design: row-major H in/out.)
__global__ __launch_bounds__(256) void gemm_kernel(
        const uint32* __restrict__ Hu, const u16b* __restrict__ WBl,
        const float* __restrict__ PARl, uint32* __restrict__ HWu,
        float* __restrict__ ssrc, float* __restrict__ sdst) {
    __shared__ float hs[64 * 129];
    __shared__ float pp[512];
    const int tid = threadIdx.x;
    const int lane = tid & 63;
    const int wave = tid >> 6;
    const int quad = lane >> 4;
    const int n0 = blockIdx.x * 64;
    const int m = n0 + wave * 16 + (lane & 15);

    const u16b* hrow = (const u16b*)Hu + (size_t)m * 128;
    short8 a0 = *(const short8*)(hrow + 0  + quad * 8);
    short8 a1 = *(const short8*)(hrow + 32 + quad * 8);
    short8 a2 = *(const short8*)(hrow + 64 + quad * 8);
    short8 a3 = *(const short8*)(hrow + 96 + quad * 8);

#pragma unroll
    for (int nt = 0; nt < 8; ++nt) {
        const u16b* bbase = WBl + ((size_t)nt * 512 + lane * 8);
        short8 b0 = *(const short8*)(bbase + 0 * 4096);
        short8 b1 = *(const short8*)(bbase + 1 * 4096);
        short8 b2 = *(const short8*)(bbase + 2 * 4096);
        short8 b3 = *(const short8*)(bbase + 3 * 4096);
        float4v acc = {0.f, 0.f, 0.f, 0.f};
        acc = __builtin_amdgcn_mfma_f32_16x16x32_bf16(a0, b0, acc, 0, 0, 0);
        acc = __builtin_amdgcn_mfma_f32_16x16x32_bf16(a1, b1, acc, 0, 0, 0);
        acc = __builtin_amdgcn_mfma_f32_16x16x32_bf16(a2, b2, acc, 0, 0, 0);
        acc = __builtin_amdgcn_mfma_f32_16x16x32_bf16(a3, b3, acc, 0, 0, 0);
#pragma unroll
        for (int r = 0; r < 4; ++r)
            hs[(wave * 16 + quad * 4 + r) * 129 + nt * 16 + (lane & 15)] = acc[r];
    }
    __syncthreads();

    {
        const int mn = tid & 63, cg = tid >> 6;
        const float* Asr = PARl + P_ASRC;
        const float* Ads = PARl + P_ADST;
        const float* row = hs + mn * 129 + cg * 32;
        float ps = 0.f, pd = 0.f;
#pragma unroll
        for (int j = 0; j < 32; ++j) {
            float v = row[j];
            ps = fmaf(v, Asr[cg * 32 + j], ps);
            pd = fmaf(v, Ads[cg * 32 + j], pd);
        }
        pp[tid] = ps; pp[256 + tid] = pd;
    }
    __syncthreads();
    if (tid < 64) {
        ssrc[n0 + tid] = pp[tid] + pp[64 + tid] + pp[128 + tid] + pp[192 + tid];
        sdst[n0 + tid] = pp[256 + tid] + pp[320 + tid] + pp[384 + tid] + pp[448 + tid];
    }

#pragma unroll
    for (int i = 0; i < 4; ++i) {
        int flat = i * 2048 + tid * 8;
        int n = flat >> 7, c = flat & 127;
        const float* p = hs + n * 129 + c;
        uint4 v;
        v.x = pack2(p[0], p[1]); v.y = pack2(p[2], p[3]);
        v.z = pack2(p[4], p[5]); v.w = pack2(p[6], p[7]);
        *(uint4*)(HWu + (size_t)(n0 + n) * 64 + c / 2) = v;
    }
}

// ---------------------------------------------------------------------------
// Hidden-layer attention + aggregation, one wave per dst node (R7 design).
// Lane-parallel softmax precompute (edge j in lane j, deg<=64 fast path),
// factored edge-feature term, readlane-broadcast gather loop.
// NT hints on the streaming CSR metadata so it doesn't evict HW rows from L2.
// Layer 3 additionally emits hw5[n] = dot(h_out[n], W5).
__global__ __launch_bounds__(256) void agg_kernel(
        const uint32* __restrict__ HWu, const float* __restrict__ ssrc,
        const float* __restrict__ sdst, const int* __restrict__ csr_src,
        const uint32* __restrict__ csr_ea, const int* __restrict__ row_ptr,
        const float* __restrict__ PAR, int layer, uint32* __restrict__ HoutU,
        float* __restrict__ hw5out, int wantw5) {
    const int lane = threadIdx.x & 63;
    const int n = blockIdx.x * 4 + (threadIdx.x >> 6);
    const int begin = __builtin_amdgcn_readfirstlane(row_ptr[n]);
    const int deg   = __builtin_amdgcn_readfirstlane(row_ptr[n + 1]) - begin;
    const float c0 = PAR[P_CVEC + 2 * layer], c1 = PAR[P_CVEC + 2 * layer + 1];
    const float sd = sdst[n];

    // phase 1: edge lane's logit (first 64 edges in-register; NT metadata)
    int   sv = 0;
    uint32 eb = 0;
    float L = -3.4e38f;
    if (lane < deg) {
        sv = __builtin_nontemporal_load(&csr_src[begin + lane]);
        eb = __builtin_nontemporal_load(&csr_ea[begin + lane]);
        L = fmaf(hi2f(eb), c1, fmaf(lo2f(eb), c0, ssrc[sv] + sd));
        L = (L > 0.f) ? L : 0.2f * L;
    }
    float m = L;
    for (int j0 = 64; j0 < deg; j0 += 64) {        // rare (deg > 64)
        int j = j0 + lane;
        if (j < deg) {
            int s2 = csr_src[begin + j];
            uint32 e2 = csr_ea[begin + j];
            float L2 = fmaf(hi2f(e2), c1, fmaf(lo2f(e2), c0, ssrc[s2] + sd));
            L2 = (L2 > 0.f) ? L2 : 0.2f * L2;
            m = fmaxf(m, L2);
        }
    }
#pragma unroll
    for (int o = 32; o; o >>= 1) m = fmaxf(m, __shfl_xor(m, o, 64));

    float ex = (lane < deg) ? __expf(L - m) : 0.f;
    float dsum = ex, sx = ex * lo2f(eb), sy = ex * hi2f(eb);
    for (int j0 = 64; j0 < deg; j0 += 64) {        // rare
        int j = j0 + lane;
        if (j < deg) {
            int s2 = csr_src[begin + j];
            uint32 e2 = csr_ea[begin + j];
            float L2 = fmaf(hi2f(e2), c1, fmaf(lo2f(e2), c0, ssrc[s2] + sd));
            L2 = (L2 > 0.f) ? L2 : 0.2f * L2;
            float x2 = __expf(L2 - m);
            dsum += x2; sx = fmaf(x2, lo2f(e2), sx); sy = fmaf(x2, hi2f(e2), sy);
        }
    }
#pragma unroll
    for (int o = 32; o; o >>= 1) {
        dsum += __shfl_xor(dsum, o, 64);
        sx   += __shfl_xor(sx, o, 64);
        sy   += __shfl_xor(sy, o, 64);
    }

    // phase 2: weighted row gather. acc = sum ex*hw[src]  (per-lane 2 channels)
    const int dmain = (deg < 64) ? deg : 64;
    const uint32 exu = __float_as_uint(ex);
    float acc0 = 0.f, acc1 = 0.f;
    int jj = 0;
    for (; jj + 8 <= dmain; jj += 8) {
        int s8[8]; float e8[8]; uint32 hv[8];
#pragma unroll
        for (int q = 0; q < 8; ++q) {
            s8[q] = __builtin_amdgcn_readlane(sv, jj + q);
            e8[q] = __uint_as_float(__builtin_amdgcn_readlane((int)exu, jj + q));
        }
#pragma unroll
        for (int q = 0; q < 8; ++q) hv[q] = HWu[(size_t)s8[q] * 64 + lane];
#pragma unroll
        for (int q = 0; q < 8; ++q) {
            acc0 = fmaf(e8[q], lo2f(hv[q]), acc0);
            acc1 = fmaf(e8[q], hi2f(hv[q]), acc1);
        }
    }
    for (; jj < dmain; ++jj) {
        int s = __builtin_amdgcn_readlane(sv, jj);
        float e1v = __uint_as_float(__builtin_amdgcn_readlane((int)exu, jj));
        uint32 hb = HWu[(size_t)s * 64 + lane];
        acc0 = fmaf(e1v, lo2f(hb), acc0);
        acc1 = fmaf(e1v, hi2f(hb), acc1);
    }
    for (jj = 64; jj < deg; ++jj) {                // rare tail
        int s = csr_src[begin + jj];
        uint32 e2 = csr_ea[begin + jj];
        float L2 = fmaf(hi2f(e2), c1, fmaf(lo2f(e2), c0, ssrc[s] + sd));
        L2 = (L2 > 0.f) ? L2 : 0.2f * L2;
        float x2 = __expf(L2 - m);
        uint32 hb = HWu[(size_t)s * 64 + lane];
        acc0 = fmaf(x2, lo2f(hb), acc0);
        acc1 = fmaf(x2, hi2f(hb), acc1);
    }

    const int ch = lane * 2;
    const float* WEl = PAR + P_WE + layer * 256;
    const float inv = 1.f / (dsum + 1e-16f);
    const float* Bl = PAR + P_BIAS + layer * DD;
    float t0 = fmaf(sy, WEl[DD + ch],     fmaf(sx, WEl[ch],     acc0));
    float t1 = fmaf(sy, WEl[DD + ch + 1], fmaf(sx, WEl[ch + 1], acc1));
    float o0 = fmaf(t0, inv, Bl[ch]);
    float o1 = fmaf(t1, inv, Bl[ch + 1]);
    o0 = (o0 > 0.f) ? o0 : 0.01f * o0;
    o1 = (o1 > 0.f) ? o1 : 0.01f * o1;
    HoutU[(size_t)n * 64 + lane] = pack2(o0, o1);

    if (wantw5) {
        float p = o0 * PAR[P_W5 + ch] + o1 * PAR[P_W5 + ch + 1];
#pragma unroll
        for (int o = 32; o; o >>= 1) p += __shfl_xor(p, o, 64);
        if (lane == 0) hw5out[n] = p;
    }
}

// ---------------------------------------------------------------------------
__global__ __launch_bounds__(256) void final_kernel(
        const float* __restrict__ hw5, const int* __restrict__ csr_src,
        const uint32* __restrict__ csr_ea, const int* __restrict__ row_ptr,
        const float* __restrict__ PAR, const int* __restrict__ FLAG,
        void* __restrict__ out) {
    const int flag = FLAG[0];
    int lane = threadIdx.x & 63;
    int n = blockIdx.x * 4 + (threadIdx.x >> 6);
    int begin = __builtin_amdgcn_readfirstlane(row_ptr[n]);
    int deg   = __builtin_amdgcn_readfirstlane(row_ptr[n + 1]) - begin;
    float c50 = PAR[P_CVEC + 8], c51 = PAR[P_CVEC + 9];
    float ce0 = PAR[P_CVEC + 10], ce1 = PAR[P_CVEC + 11];
    float b5v = PAR[P_SC5], a5s = PAR[P_SC5 + 1];
    float hd = PAR[P_SC5 + 2] * hw5[n];

    float m = -3.4e38f;
    for (int j0 = 0; j0 < deg; j0 += 64) {
        int j = j0 + lane;
        if (j < deg) {
            int s = csr_src[begin + j];
            uint32 eb = csr_ea[begin + j];
            float L = fmaf(hi2f(eb), c51, fmaf(lo2f(eb), c50, fmaf(a5s, hw5[s], hd)));
            L = (L > 0.f) ? L : 0.2f * L;
            m = fmaxf(m, L);
        }
    }
#pragma unroll
    for (int o = 32; o; o >>= 1) m = fmaxf(m, __shfl_xor(m, o, 64));

    float dsum = 0.f, msum = 0.f;
    for (int j0 = 0; j0 < deg; j0 += 64) {
        int j = j0 + lane;
        if (j < deg) {
            int s = csr_src[begin + j];
            uint32 eb = csr_ea[begin + j];
            float hs5 = hw5[s];
            float L = fmaf(hi2f(eb), c51, fmaf(lo2f(eb), c50, fmaf(a5s, hs5, hd)));
            L = (L > 0.f) ? L : 0.2f * L;
            float ex = __expf(L - m);
            dsum += ex;
            msum = fmaf(ex, hs5 + fmaf(hi2f(eb), ce1, lo2f(eb) * ce0), msum);
        }
    }
#pragma unroll
    for (int o = 32; o; o >>= 1) {
        dsum += __shfl_xor(dsum, o, 64);
        msum += __shfl_xor(msum, o, 64);
    }
    if (lane == 0) {
        float r = msum / (dsum + 1e-16f) + b5v;
        if (flag) ((float*)out)[n] = r;
        else      ((u16b*)out)[n] = (u16b)f2bf_bits(r);
    }
}

// ---------------------------------------------------------------------------
extern "C" void kernel_launch(void* const* d_in, const int* in_sizes, int n_in,
                              void* d_out, int out_size, void* d_ws, size_t ws_size,
                              hipStream_t stream) {
    const void* x   = d_in[0];
    const int*  ei  = (const int*)d_in[1];
    const void* ea  = d_in[2];
    const int*  cur = (const int*)d_in[3];
    const void* vge = d_in[4];
    const void* vnd = d_in[5];
    const void* pW  = d_in[6];
    const void* pb  = d_in[7];
    const void* Ws  = d_in[8];
    const void* bs  = d_in[9];
    const void* asr = d_in[10];
    const void* ads = d_in[11];
    const void* aeg = d_in[12];
    const void* Wes = d_in[13];
    const void* W5  = d_in[14];
    const void* b5  = d_in[15];
    const void* as5 = d_in[16];
    const void* ad5 = d_in[17];
    const void* ae5 = d_in[18];
    const void* We5 = d_in[19];
    (void)in_sizes; (void)n_in; (void)out_size;

    const int* e_src = ei;
    const int* e_dst = ei + EE;

    size_t off = 0;
    char* base = (char*)d_ws;
    auto carve = [&](size_t bytes) {
        void* p = base + off;
        off += (bytes + 255) & ~(size_t)255;
        return p;
    };
    int*    FLAG   = (int*)carve(256);
    float*  PAR    = (float*)carve((size_t)P_TOT * 4);
    u16b*   WB     = (u16b*)carve(4 * DD * DD * 2);
    uint32* H0     = (uint32*)carve((size_t)NV * DD * 2);
    uint32* H1     = (uint32*)carve((size_t)NV * DD * 2); // also bucket storage
    float*  SS     = (float*)carve(NV * 4);
    float*  SD     = (float*)carve(NV * 4);
    float*  HW5v   = (float*)carve(NV * 4);
    int*    COUNTS = (int*)carve(65536 * 4);
    int*    ROWPTR = (int*)carve(65536 * 4);
    int*    GCUR   = (int*)carve(256 * 4);
    int*    PART   = (int*)carve(256 * 4);
    int*    BOFF   = (int*)carve(256 * 4);
    int*    CSRS   = (int*)carve((size_t)EE * 4);
    uint32* CSREA  = (uint32*)carve((size_t)EE * 4);
    size_t need = off;

    uint32* BUKX = H1;
    uint32* BUKY = H1 + (size_t)NBUK * BCAP;

    sniff_kernel<<<1, 256, 0, stream>>>((const unsigned short*)ea, FLAG);

    if (need > ws_size) {
        zero_out_kernel<<<(NV + 255) / 256, 256, 0, stream>>>(
            d_out, FLAG, (float)(ws_size >> 20));
        return;
    }

    prep_kernel<<<5, 256, 0, stream>>>(Wes, aeg, We5, ae5, asr, ads, bs,
                                       W5, b5, as5, ad5, FLAG, PAR);
    prepack_kernel<<<32, 256, 0, stream>>>(Ws, FLAG, WB);
    proj_kernel<<<NV / 4, 256, 0, stream>>>(x, pW, pb, cur, vge, vnd, FLAG, H0);

    init_kernel<<<2, 256, 0, stream>>>(GCUR, COUNTS);
    bucketize_kernel<<<EE / 4096, 256, 0, stream>>>(e_src, e_dst, ea, FLAG,
                                                    GCUR, BUKX, BUKY);
    bcount_kernel<<<NBUK, 256, 0, stream>>>(BUKX, GCUR, COUNTS);
    scan1_kernel<<<63, 256, 0, stream>>>(COUNTS, ROWPTR, PART);
    scan2_kernel<<<1, 64, 0, stream>>>(PART, BOFF, 63);
    scan3_kernel<<<63, 256, 0, stream>>>(ROWPTR, BOFF);
    bscatter_kernel<<<NBUK, 256, 0, stream>>>(BUKX, BUKY, GCUR, ROWPTR,
                                              CSRS, CSREA);

    for (int l = 0; l < 4; ++l) {
        gemm_kernel<<<NV / 64, 256, 0, stream>>>(
            H0, WB + (size_t)l * 16384, PAR + l * DD, H1, SS, SD);
        agg_kernel<<<NV / 4, 256, 0, stream>>>(
            H1, SS, SD, CSRS, CSREA, ROWPTR, PAR, l, H0, HW5v, (l == 3) ? 1 : 0);
    }

    final_kernel<<<NV / 4, 256, 0, stream>>>(HW5v, CSRS, CSREA, ROWPTR, PAR,
                                             FLAG, d_out);
}